// Round 1
// baseline (1140.002 us; speedup 1.0000x reference)
//
#include <hip/hip_runtime.h>
#include <hip/hip_bf16.h>
#include <math.h>

#define NN_NODES 50000
#define NE_EDGES 600000
#define DIM 128
#define HID 256
#define EPS_MSG 1e-7f
#define EPS_NORM 1e-5f

// ---------------- node encoder: h[n,d] = x[n]*Wn[d] + bn_b[d] ----------------
__global__ void k_encode(const float* __restrict__ x, const float* __restrict__ Wn,
                         const float* __restrict__ bnb, float* __restrict__ h, int total) {
    int i = blockIdx.x * blockDim.x + threadIdx.x;
    if (i >= total) return;
    int d = i & (DIM - 1);
    int n = i >> 7;
    h[i] = fmaf(x[n], Wn[d], bnb[d]);
}

// ---------------- CSR build ----------------
__global__ void k_hist(const int* __restrict__ dst, int* __restrict__ deg, int E) {
    int i = blockIdx.x * blockDim.x + threadIdx.x;
    if (i < E) atomicAdd(&deg[dst[i]], 1);
}

__global__ __launch_bounds__(1024) void k_scan(const int* __restrict__ deg,
                                               int* __restrict__ row_off,
                                               int* __restrict__ cursor, int n) {
    __shared__ int wsum[16];
    __shared__ int carry;
    if (threadIdx.x == 0) carry = 0;
    __syncthreads();
    int lane = threadIdx.x & 63;
    int wid = threadIdx.x >> 6;
    for (int base = 0; base < n; base += 1024) {
        int i = base + (int)threadIdx.x;
        int v = (i < n) ? deg[i] : 0;
        int x = v;
        #pragma unroll
        for (int off = 1; off < 64; off <<= 1) {
            int y = __shfl_up(x, off, 64);
            if (lane >= off) x += y;
        }
        if (lane == 63) wsum[wid] = x;
        __syncthreads();
        if (wid == 0 && lane < 16) {
            int w = wsum[lane];
            #pragma unroll
            for (int off = 1; off < 16; off <<= 1) {
                int y = __shfl_up(w, off, 64);
                if (lane >= off) w += y;
            }
            wsum[lane] = w;
        }
        __syncthreads();
        int prev = (wid == 0) ? 0 : wsum[wid - 1];
        int excl = carry + prev + (x - v);
        if (i < n) { row_off[i] = excl; cursor[i] = excl; }
        int chunk_total = wsum[15];
        __syncthreads();
        if (threadIdx.x == 0) carry += chunk_total;
        __syncthreads();
    }
    if (threadIdx.x == 0) row_off[n] = carry;
}

__global__ void k_scatter(const int* __restrict__ src, const int* __restrict__ dst,
                          const float* __restrict__ eattr, int* __restrict__ cursor,
                          int* __restrict__ col_src, float* __restrict__ ea_perm, int E) {
    int i = blockIdx.x * blockDim.x + threadIdx.x;
    if (i >= E) return;
    int d = dst[i];
    int pos = atomicAdd(&cursor[d], 1);
    col_src[pos] = src[i];
    ea_perm[pos] = eattr[i];
}

// ---------------- BatchNorm ----------------
__global__ void k_bn_stats(const float* __restrict__ h, float* __restrict__ stats, int N) {
    int d = threadIdx.x & (DIM - 1);
    int rsub = threadIdx.x >> 7;                 // 0..1
    int stride = gridDim.x * 2;
    float s = 0.f, sq = 0.f;
    for (int r = blockIdx.x * 2 + rsub; r < N; r += stride) {
        float v = h[(size_t)r * DIM + d];
        s += v;
        sq += v * v;
    }
    atomicAdd(&stats[d], s);
    atomicAdd(&stats[DIM + d], sq);
}

__global__ void k_bn_final(const float* __restrict__ stats, const float* __restrict__ gamma,
                           const float* __restrict__ beta, float* __restrict__ scl, int N) {
    int d = threadIdx.x;  // 128
    float mu = stats[d] / (float)N;
    float var = stats[DIM + d] / (float)N - mu * mu;
    float rstd = rsqrtf(var + EPS_NORM);
    float sc = rstd * gamma[d];
    scl[d] = sc;
    scl[DIM + d] = beta[d] - mu * sc;
}

__global__ void k_bn_relu(const float* __restrict__ h, const float* __restrict__ scl,
                          float* __restrict__ hn, int total) {
    int i = blockIdx.x * blockDim.x + threadIdx.x;
    if (i >= total) return;
    int d = i & (DIM - 1);
    float v = fmaf(h[i], scl[d], scl[DIM + d]);
    hn[i] = fmaxf(v, 0.f);
}

// ---------------- GENConv softmax aggregation (per-node block, thread = channel) -------
__global__ __launch_bounds__(128) void k_agg(const float* __restrict__ hn,
                                             const float* __restrict__ ea_perm,
                                             const int* __restrict__ col_src,
                                             const int* __restrict__ row_off,
                                             const float* __restrict__ We,
                                             const float* __restrict__ be,
                                             const float* __restrict__ t_all, int l,
                                             float* __restrict__ ob, int N) {
    int n = blockIdx.x;
    int d = threadIdx.x;  // 128
    int p0 = row_off[n];
    int p1 = row_off[n + 1];
    float we = We[d], bed = be[d];
    float t = t_all[l];

    float m = -INFINITY;
    for (int p = p0; p < p1; ++p) {
        int s = col_src[p];
        float ea = ea_perm[p];
        float msg = hn[(size_t)s * DIM + d] + fmaf(ea, we, bed - hn[(size_t)s * DIM + d]);
        // NOTE: simpler direct form below; above line kept simple:
        msg = fmaf(ea, we, bed) + hn[(size_t)s * DIM + d];
        msg = fmaxf(msg, 0.f) + EPS_MSG;
        m = fmaxf(m, msg * t);
    }
    float den = 0.f, num = 0.f;
    for (int p = p0; p < p1; ++p) {
        int s = col_src[p];
        float ea = ea_perm[p];
        float msg = fmaf(ea, we, bed) + hn[(size_t)s * DIM + d];
        msg = fmaxf(msg, 0.f) + EPS_MSG;
        float ex = __expf(msg * t - m);
        den += ex;
        num += msg * ex;
    }
    float agg = (p1 > p0) ? num / (den + 1e-16f) : 0.f;
    ob[(size_t)n * DIM + d] = agg + hn[(size_t)n * DIM + d];
}

// ---------------- fp32 GEMM: C[M,NN] = A[M,K] @ B[K,NN] (+bias) (+=) ----------------
// BM=64, BN=64, BK=128, 256 threads, 4x4 micro-tile per thread.
template <int EPI>  // 0: C = acc + bias ; 1: C += acc + bias
__global__ __launch_bounds__(256, 2) void k_gemm(const float* __restrict__ A,
                                                 const float* __restrict__ B,
                                                 const float* __restrict__ bias,
                                                 float* __restrict__ C,
                                                 int M, int NCOLS, int K) {
    const int LDA = 65;  // pad to kill bank conflicts on scalar reads/writes
    __shared__ float As[128 * LDA];   // 33.3 KB, As[k][m]
    __shared__ float Bs[128 * 64];    // 32 KB,   Bs[k][n]
    int row0 = blockIdx.x * 64;
    int col0 = blockIdx.y * 64;
    int tid = threadIdx.x;
    int tm = tid >> 4;   // 0..15
    int tn = tid & 15;   // 0..15
    float acc[4][4] = {{0.f}};

    for (int k0 = 0; k0 < K; k0 += 128) {
        #pragma unroll
        for (int i = 0; i < 32; ++i) {
            int idx = tid + i * 256;
            int m = idx >> 7;
            int k = idx & 127;
            int gr = row0 + m;
            float v = (gr < M) ? A[(size_t)gr * K + k0 + k] : 0.f;
            As[k * LDA + m] = v;
        }
        #pragma unroll
        for (int i = 0; i < 32; ++i) {
            int idx = tid + i * 256;
            int k = idx >> 6;
            int nn = idx & 63;
            Bs[k * 64 + nn] = B[(size_t)(k0 + k) * NCOLS + col0 + nn];
        }
        __syncthreads();
        #pragma unroll 8
        for (int k = 0; k < 128; ++k) {
            const float* ap = &As[k * LDA + tm * 4];
            float a0 = ap[0], a1 = ap[1], a2 = ap[2], a3 = ap[3];
            float4 b = *(const float4*)&Bs[k * 64 + tn * 4];
            acc[0][0] = fmaf(a0, b.x, acc[0][0]);
            acc[0][1] = fmaf(a0, b.y, acc[0][1]);
            acc[0][2] = fmaf(a0, b.z, acc[0][2]);
            acc[0][3] = fmaf(a0, b.w, acc[0][3]);
            acc[1][0] = fmaf(a1, b.x, acc[1][0]);
            acc[1][1] = fmaf(a1, b.y, acc[1][1]);
            acc[1][2] = fmaf(a1, b.z, acc[1][2]);
            acc[1][3] = fmaf(a1, b.w, acc[1][3]);
            acc[2][0] = fmaf(a2, b.x, acc[2][0]);
            acc[2][1] = fmaf(a2, b.y, acc[2][1]);
            acc[2][2] = fmaf(a2, b.z, acc[2][2]);
            acc[2][3] = fmaf(a2, b.w, acc[2][3]);
            acc[3][0] = fmaf(a3, b.x, acc[3][0]);
            acc[3][1] = fmaf(a3, b.y, acc[3][1]);
            acc[3][2] = fmaf(a3, b.z, acc[3][2]);
            acc[3][3] = fmaf(a3, b.w, acc[3][3]);
        }
        __syncthreads();
    }

    int colb = col0 + tn * 4;
    float4 bb = *(const float4*)&bias[colb];
    #pragma unroll
    for (int r = 0; r < 4; ++r) {
        int gr = row0 + tm * 4 + r;
        if (gr >= M) break;
        float4* cp = (float4*)&C[(size_t)gr * NCOLS + colb];
        float4 v;
        v.x = acc[r][0] + bb.x;
        v.y = acc[r][1] + bb.y;
        v.z = acc[r][2] + bb.z;
        v.w = acc[r][3] + bb.w;
        if (EPI == 1) {
            float4 old = *cp;
            v.x += old.x; v.y += old.y; v.z += old.z; v.w += old.w;
        }
        *cp = v;
    }
}

// ---------------- LayerNorm(H=256) + ReLU, in place on z1. Wave per row. ----------------
__global__ __launch_bounds__(256) void k_ln_relu(float* __restrict__ z,
                                                 const float* __restrict__ g,
                                                 const float* __restrict__ b, int N) {
    int row = blockIdx.x * 4 + (threadIdx.x >> 6);
    int lane = threadIdx.x & 63;
    if (row >= N) return;
    float4* zp = (float4*)(z + (size_t)row * HID);
    float4 v = zp[lane];
    float s = v.x + v.y + v.z + v.w;
    float sq = v.x * v.x + v.y * v.y + v.z * v.z + v.w * v.w;
    #pragma unroll
    for (int off = 32; off >= 1; off >>= 1) {
        s += __shfl_xor(s, off, 64);
        sq += __shfl_xor(sq, off, 64);
    }
    float mu = s * (1.f / HID);
    float var = sq * (1.f / HID) - mu * mu;
    float rstd = rsqrtf(var + EPS_NORM);
    const float4 gg = ((const float4*)g)[lane];
    const float4 bb = ((const float4*)b)[lane];
    float4 o;
    o.x = fmaxf(fmaf((v.x - mu) * rstd, gg.x, bb.x), 0.f);
    o.y = fmaxf(fmaf((v.y - mu) * rstd, gg.y, bb.y), 0.f);
    o.z = fmaxf(fmaf((v.z - mu) * rstd, gg.z, bb.z), 0.f);
    o.w = fmaxf(fmaf((v.w - mu) * rstd, gg.w, bb.w), 0.f);
    zp[lane] = o;
}

// ---------------- edge dot predictor: out[e] = dot(h[src], h[dst]) ----------------
__global__ __launch_bounds__(256) void k_dot(const float* __restrict__ h,
                                             const int* __restrict__ src,
                                             const int* __restrict__ dst,
                                             float* __restrict__ out, int E) {
    int e = blockIdx.x * 4 + (threadIdx.x >> 6);
    int lane = threadIdx.x & 63;
    if (e >= E) return;
    int s = src[e], d = dst[e];
    float2 a = ((const float2*)(h + (size_t)s * DIM))[lane];
    float2 b = ((const float2*)(h + (size_t)d * DIM))[lane];
    float p = a.x * b.x + a.y * b.y;
    #pragma unroll
    for (int off = 32; off >= 1; off >>= 1) p += __shfl_xor(p, off, 64);
    if (lane == 0) out[e] = p;
}

extern "C" void kernel_launch(void* const* d_in, const int* in_sizes, int n_in,
                              void* d_out, int out_size, void* d_ws, size_t ws_size,
                              hipStream_t stream) {
    const float* x        = (const float*)d_in[0];
    const int*   ei       = (const int*)d_in[1];
    const float* eattr    = (const float*)d_in[2];
    const float* Wn       = (const float*)d_in[3];
    const float* bnb      = (const float*)d_in[4];
    const float* We       = (const float*)d_in[5];
    const float* be       = (const float*)d_in[6];
    const float* bn_gamma = (const float*)d_in[7];
    const float* bn_beta  = (const float*)d_in[8];
    const float* t_all    = (const float*)d_in[9];
    const float* W1       = (const float*)d_in[10];
    const float* b1       = (const float*)d_in[11];
    const float* ln_g     = (const float*)d_in[12];
    const float* ln_b     = (const float*)d_in[13];
    const float* W2       = (const float*)d_in[14];
    const float* b2       = (const float*)d_in[15];
    float* out = (float*)d_out;

    const int N = NN_NODES, E = NE_EDGES, D = DIM, H = HID;
    const int* src = ei;
    const int* dst = ei + E;

    char* ws = (char*)d_ws;
    auto alloc = [&](size_t bytes) {
        char* p = ws;
        ws += (bytes + 255) & ~(size_t)255;
        return p;
    };
    float* h       = (float*)alloc((size_t)N * D * 4);
    float* hn      = (float*)alloc((size_t)N * D * 4);
    float* ob      = (float*)alloc((size_t)N * D * 4);
    float* z1      = (float*)alloc((size_t)N * H * 4);
    int*   col_src = (int*)alloc((size_t)E * 4);
    float* ea_perm = (float*)alloc((size_t)E * 4);
    int*   row_off = (int*)alloc((size_t)(N + 1) * 4);
    int*   cursor  = (int*)alloc((size_t)N * 4);
    int*   deg     = (int*)alloc((size_t)N * 4);
    float* stats   = (float*)alloc((size_t)2 * D * 4);
    float* scl     = (float*)alloc((size_t)2 * D * 4);

    hipMemsetAsync(deg, 0, (size_t)N * 4, stream);
    k_encode<<<(N * D + 255) / 256, 256, 0, stream>>>(x, Wn, bnb, h, N * D);
    k_hist<<<(E + 255) / 256, 256, 0, stream>>>(dst, deg, E);
    k_scan<<<1, 1024, 0, stream>>>(deg, row_off, cursor, N);
    k_scatter<<<(E + 255) / 256, 256, 0, stream>>>(src, dst, eattr, cursor, col_src, ea_perm, E);

    for (int l = 0; l < 2; ++l) {
        hipMemsetAsync(stats, 0, (size_t)2 * D * 4, stream);
        k_bn_stats<<<256, 256, 0, stream>>>(h, stats, N);
        k_bn_final<<<1, 128, 0, stream>>>(stats, bn_gamma + l * D, bn_beta + l * D, scl, N);
        k_bn_relu<<<(N * D + 255) / 256, 256, 0, stream>>>(h, scl, hn, N * D);
        k_agg<<<N, 128, 0, stream>>>(hn, ea_perm, col_src, row_off, We, be, t_all, l, ob, N);
        dim3 g1((N + 63) / 64, H / 64);
        k_gemm<0><<<g1, 256, 0, stream>>>(ob, W1 + (size_t)l * D * H, b1 + l * H, z1, N, H, D);
        k_ln_relu<<<(N + 3) / 4, 256, 0, stream>>>(z1, ln_g + l * H, ln_b + l * H, N);
        dim3 g2((N + 63) / 64, D / 64);
        k_gemm<1><<<g2, 256, 0, stream>>>(z1, W2 + (size_t)l * H * D, b2 + l * D, h, N, D, H);
    }
    k_dot<<<(E + 3) / 4, 256, 0, stream>>>(h, src, dst, out, E);
}

// Round 2
// 742.278 us; speedup vs baseline: 1.5358x; 1.5358x over previous
//
#include <hip/hip_runtime.h>
#include <hip/hip_bf16.h>
#include <math.h>

#define NN_NODES 50000
#define NE_EDGES 600000
#define MPAD     50048      // 391 * 128
#define DIM 128
#define HID 256
#define EPS_MSG 1e-7f
#define EPS_NORM 1e-5f

typedef __attribute__((ext_vector_type(8))) short short8v;
typedef __attribute__((ext_vector_type(4))) float f32x4;

__device__ inline ushort f2bf(float f) {
    union { float f; unsigned u; } v; v.f = f;
    unsigned r = v.u + 0x7FFF + ((v.u >> 16) & 1);
    return (ushort)(r >> 16);
}

// ---------------- node encoder: h[n,d] = x[n]*Wn[d] + bn_b[d] ----------------
__global__ void k_encode(const float* __restrict__ x, const float* __restrict__ Wn,
                         const float* __restrict__ bnb, float* __restrict__ h, int total) {
    int i = blockIdx.x * blockDim.x + threadIdx.x;
    if (i >= total) return;
    int d = i & (DIM - 1);
    int n = i >> 7;
    h[i] = fmaf(x[n], Wn[d], bnb[d]);
}

// ---------------- weight cast + transpose: in[R][C] fp32 -> out[C][R] bf16 ----------------
__global__ void k_castT(const float* __restrict__ in, ushort* __restrict__ out, int R, int C) {
    int i = blockIdx.x * blockDim.x + threadIdx.x;
    if (i >= R * C) return;
    int r = i / C, c = i - r * C;
    out[(size_t)c * R + r] = f2bf(in[i]);
}

// ---------------- CSR build ----------------
__global__ void k_hist(const int* __restrict__ dst, int* __restrict__ deg, int E) {
    int i = blockIdx.x * blockDim.x + threadIdx.x;
    if (i < E) atomicAdd(&deg[dst[i]], 1);
}

__global__ __launch_bounds__(1024) void k_scan(const int* __restrict__ deg,
                                               int* __restrict__ row_off,
                                               int* __restrict__ cursor, int n) {
    __shared__ int wsum[16];
    __shared__ int carry;
    if (threadIdx.x == 0) carry = 0;
    __syncthreads();
    int lane = threadIdx.x & 63;
    int wid = threadIdx.x >> 6;
    for (int base = 0; base < n; base += 1024) {
        int i = base + (int)threadIdx.x;
        int v = (i < n) ? deg[i] : 0;
        int x = v;
        #pragma unroll
        for (int off = 1; off < 64; off <<= 1) {
            int y = __shfl_up(x, off, 64);
            if (lane >= off) x += y;
        }
        if (lane == 63) wsum[wid] = x;
        __syncthreads();
        if (wid == 0 && lane < 16) {
            int w = wsum[lane];
            #pragma unroll
            for (int off = 1; off < 16; off <<= 1) {
                int y = __shfl_up(w, off, 64);
                if (lane >= off) w += y;
            }
            wsum[lane] = w;
        }
        __syncthreads();
        int prev = (wid == 0) ? 0 : wsum[wid - 1];
        int excl = carry + prev + (x - v);
        if (i < n) { row_off[i] = excl; cursor[i] = excl; }
        int chunk_total = wsum[15];
        __syncthreads();
        if (threadIdx.x == 0) carry += chunk_total;
        __syncthreads();
    }
    if (threadIdx.x == 0) row_off[n] = carry;
}

__global__ void k_scatter(const int* __restrict__ src, const int* __restrict__ dst,
                          const float* __restrict__ eattr, int* __restrict__ cursor,
                          int* __restrict__ col_src, float* __restrict__ ea_perm, int E) {
    int i = blockIdx.x * blockDim.x + threadIdx.x;
    if (i >= E) return;
    int d = dst[i];
    int pos = atomicAdd(&cursor[d], 1);
    col_src[pos] = src[i];
    ea_perm[pos] = eattr[i];
}

// ---------------- BatchNorm stats ----------------
__global__ void k_bn_stats(const float* __restrict__ h, float* __restrict__ stats, int N) {
    int d = threadIdx.x & (DIM - 1);
    int rsub = threadIdx.x >> 7;
    int stride = gridDim.x * 2;
    float s = 0.f, sq = 0.f;
    for (int r = blockIdx.x * 2 + rsub; r < N; r += stride) {
        float v = h[(size_t)r * DIM + d];
        s += v;
        sq += v * v;
    }
    atomicAdd(&stats[d], s);
    atomicAdd(&stats[DIM + d], sq);
}

__global__ void k_bn_final(const float* __restrict__ stats, const float* __restrict__ gamma,
                           const float* __restrict__ beta, float* __restrict__ scl, int N) {
    int d = threadIdx.x;  // 128
    float mu = stats[d] / (float)N;
    float var = stats[DIM + d] / (float)N - mu * mu;
    float rstd = rsqrtf(var + EPS_NORM);
    float sc = rstd * gamma[d];
    scl[d] = sc;
    scl[DIM + d] = beta[d] - mu * sc;
}

// ------------- GENConv softmax aggregation, BN+ReLU fused, single pass -------------
// block = node, thread = channel. ob written as bf16 (GEMM1 A-operand).
__global__ __launch_bounds__(128) void k_agg(const float* __restrict__ h,
                                             const float* __restrict__ scl,
                                             const float* __restrict__ ea_perm,
                                             const int* __restrict__ col_src,
                                             const int* __restrict__ row_off,
                                             const float* __restrict__ We,
                                             const float* __restrict__ be,
                                             const float* __restrict__ t_all, int l,
                                             ushort* __restrict__ ob, int N) {
    int n = blockIdx.x;
    int d = threadIdx.x;  // 128
    int p0 = row_off[n];
    int p1 = row_off[n + 1];
    float sc = scl[d], of = scl[DIM + d];
    float we = We[d], bed = be[d];
    float t = t_all[l];

    // single pass: agg = sum(msg*e^{msg t}) / sum(e^{msg t})  (max-shift cancels;
    // BN output is unit-variance so msg*t ~ <=8, no fp32 exp overflow)
    float den = 0.f, num = 0.f;
    for (int p = p0; p < p1; ++p) {
        int s = col_src[p];
        float ea = ea_perm[p];
        float hh = fmaxf(fmaf(h[(size_t)s * DIM + d], sc, of), 0.f);
        float msg = fmaxf(fmaf(ea, we, bed) + hh, 0.f) + EPS_MSG;
        float ex = __expf(msg * t);
        den += ex;
        num += msg * ex;
    }
    float hroot = fmaxf(fmaf(h[(size_t)n * DIM + d], sc, of), 0.f);
    float agg = (p1 > p0) ? num / (den + 1e-16f) : 0.f;
    ob[(size_t)n * DIM + d] = f2bf(agg + hroot);
}

// ---------------- bf16 MFMA GEMM: C[M,NCOLS] = A[M,K] @ Bt[NCOLS,K]^T + bias ----------------
// BM=BN=128, BK=128, 256 threads = 4 waves, wave computes 64x64 via 4x4 16x16x32 fragments.
template <int EPI>  // 0: C = acc + bias ; 1: C += acc + bias
__global__ __launch_bounds__(256, 2) void k_gemm_mfma(const ushort* __restrict__ A,
                                                      const ushort* __restrict__ Bt,
                                                      const float* __restrict__ bias,
                                                      float* __restrict__ C,
                                                      int M, int NCOLS, int K) {
    constexpr int LDT = 136;  // row pad +8 bf16 (16B): rows land 4 banks apart -> 2-way max
    __shared__ ushort As[128 * LDT];
    __shared__ ushort Bs[128 * LDT];
    const int tid = threadIdx.x;
    const int row0 = blockIdx.x * 128;
    const int col0 = blockIdx.y * 128;
    const int wid = tid >> 6;
    const int lane = tid & 63;
    const int wr = (wid >> 1) * 64;
    const int wc = (wid & 1) * 64;
    const int l15 = lane & 15;
    const int lq = lane >> 4;
    f32x4 acc[4][4] = {};

    for (int k0 = 0; k0 < K; k0 += 128) {
        float4 va[8], vb[8];
        #pragma unroll
        for (int i = 0; i < 8; ++i) {
            int idx = tid + i * 256;       // 0..2047 groups of 8 bf16
            int r = idx >> 4;              // 0..127
            int c8 = (idx & 15) * 8;       // 0..120
            va[i] = *(const float4*)(A + (size_t)(row0 + r) * K + k0 + c8);
            vb[i] = *(const float4*)(Bt + (size_t)(col0 + r) * K + k0 + c8);
        }
        if (k0) __syncthreads();
        #pragma unroll
        for (int i = 0; i < 8; ++i) {
            int idx = tid + i * 256;
            int r = idx >> 4;
            int c8 = (idx & 15) * 8;
            *(float4*)(As + r * LDT + c8) = va[i];
            *(float4*)(Bs + r * LDT + c8) = vb[i];
        }
        __syncthreads();
        #pragma unroll
        for (int ks = 0; ks < 4; ++ks) {
            int kk = ks * 32 + lq * 8;
            short8v af[4], bf[4];
            #pragma unroll
            for (int f = 0; f < 4; ++f) {
                af[f] = *(const short8v*)(As + (wr + f * 16 + l15) * LDT + kk);
                bf[f] = *(const short8v*)(Bs + (wc + f * 16 + l15) * LDT + kk);
            }
            #pragma unroll
            for (int mi = 0; mi < 4; ++mi)
                #pragma unroll
                for (int ni = 0; ni < 4; ++ni)
                    acc[mi][ni] = __builtin_amdgcn_mfma_f32_16x16x32_bf16(
                        af[mi], bf[ni], acc[mi][ni], 0, 0, 0);
        }
    }

    // epilogue: C/D layout col=lane&15, row=(lane>>4)*4+j
    #pragma unroll
    for (int ni = 0; ni < 4; ++ni) {
        int col = col0 + wc + ni * 16 + l15;
        float bv = bias[col];
        #pragma unroll
        for (int mi = 0; mi < 4; ++mi) {
            int rowb = row0 + wr + mi * 16 + lq * 4;
            #pragma unroll
            for (int j = 0; j < 4; ++j) {
                float* cp = &C[(size_t)(rowb + j) * NCOLS + col];
                float v = acc[mi][ni][j] + bv;
                if (EPI) v += *cp;
                *cp = v;
            }
        }
    }
}

// ---------------- LayerNorm(H=256) + ReLU: z1 fp32 -> z1r bf16. Wave per row. ----------------
__global__ __launch_bounds__(256) void k_ln_relu(const float* __restrict__ z,
                                                 ushort* __restrict__ zr,
                                                 const float* __restrict__ g,
                                                 const float* __restrict__ b, int N) {
    int row = blockIdx.x * 4 + (threadIdx.x >> 6);
    int lane = threadIdx.x & 63;
    if (row >= N) return;
    const float4* zp = (const float4*)(z + (size_t)row * HID);
    float4 v = zp[lane];
    float s = v.x + v.y + v.z + v.w;
    float sq = v.x * v.x + v.y * v.y + v.z * v.z + v.w * v.w;
    #pragma unroll
    for (int off = 32; off >= 1; off >>= 1) {
        s += __shfl_xor(s, off, 64);
        sq += __shfl_xor(sq, off, 64);
    }
    float mu = s * (1.f / HID);
    float var = sq * (1.f / HID) - mu * mu;
    float rstd = rsqrtf(var + EPS_NORM);
    const float4 gg = ((const float4*)g)[lane];
    const float4 bb = ((const float4*)b)[lane];
    ushort4 o;
    o.x = f2bf(fmaxf(fmaf((v.x - mu) * rstd, gg.x, bb.x), 0.f));
    o.y = f2bf(fmaxf(fmaf((v.y - mu) * rstd, gg.y, bb.y), 0.f));
    o.z = f2bf(fmaxf(fmaf((v.z - mu) * rstd, gg.z, bb.z), 0.f));
    o.w = f2bf(fmaxf(fmaf((v.w - mu) * rstd, gg.w, bb.w), 0.f));
    ((ushort4*)(zr + (size_t)row * HID))[lane] = o;
}

// ---------------- edge dot predictor: out[e] = dot(h[src], h[dst]) ----------------
__global__ __launch_bounds__(256) void k_dot(const float* __restrict__ h,
                                             const int* __restrict__ src,
                                             const int* __restrict__ dst,
                                             float* __restrict__ out, int E) {
    int e = blockIdx.x * 4 + (threadIdx.x >> 6);
    int lane = threadIdx.x & 63;
    if (e >= E) return;
    int s = src[e], d = dst[e];
    float2 a = ((const float2*)(h + (size_t)s * DIM))[lane];
    float2 b = ((const float2*)(h + (size_t)d * DIM))[lane];
    float p = a.x * b.x + a.y * b.y;
    #pragma unroll
    for (int off = 32; off >= 1; off >>= 1) p += __shfl_xor(p, off, 64);
    if (lane == 0) out[e] = p;
}

extern "C" void kernel_launch(void* const* d_in, const int* in_sizes, int n_in,
                              void* d_out, int out_size, void* d_ws, size_t ws_size,
                              hipStream_t stream) {
    const float* x        = (const float*)d_in[0];
    const int*   ei       = (const int*)d_in[1];
    const float* eattr    = (const float*)d_in[2];
    const float* Wn       = (const float*)d_in[3];
    const float* bnb      = (const float*)d_in[4];
    const float* We       = (const float*)d_in[5];
    const float* be       = (const float*)d_in[6];
    const float* bn_gamma = (const float*)d_in[7];
    const float* bn_beta  = (const float*)d_in[8];
    const float* t_all    = (const float*)d_in[9];
    const float* W1       = (const float*)d_in[10];
    const float* b1       = (const float*)d_in[11];
    const float* ln_g     = (const float*)d_in[12];
    const float* ln_b     = (const float*)d_in[13];
    const float* W2       = (const float*)d_in[14];
    const float* b2       = (const float*)d_in[15];
    float* out = (float*)d_out;

    const int N = NN_NODES, E = NE_EDGES, D = DIM, H = HID;
    const int* src = ei;
    const int* dst = ei + E;

    char* ws = (char*)d_ws;
    auto alloc = [&](size_t bytes) {
        char* p = ws;
        ws += (bytes + 255) & ~(size_t)255;
        return p;
    };
    float*  h       = (float*)alloc((size_t)MPAD * D * 4);
    float*  z1      = (float*)alloc((size_t)MPAD * H * 4);
    ushort* ob      = (ushort*)alloc((size_t)MPAD * D * 2);
    ushort* z1r     = (ushort*)alloc((size_t)MPAD * H * 2);
    ushort* W1t     = (ushort*)alloc((size_t)2 * D * H * 2);
    ushort* W2t     = (ushort*)alloc((size_t)2 * D * H * 2);
    int*    col_src = (int*)alloc((size_t)E * 4);
    float*  ea_perm = (float*)alloc((size_t)E * 4);
    int*    row_off = (int*)alloc((size_t)(N + 1) * 4);
    int*    cursor  = (int*)alloc((size_t)N * 4);
    int*    deg     = (int*)alloc((size_t)N * 4);
    float*  stats   = (float*)alloc((size_t)2 * D * 4);
    float*  scl     = (float*)alloc((size_t)2 * D * 4);

    hipMemsetAsync(deg, 0, (size_t)N * 4, stream);
    k_encode<<<(N * D + 255) / 256, 256, 0, stream>>>(x, Wn, bnb, h, N * D);
    // weights: W1 [D][H] -> W1t [H][D]; W2 [H][D] -> W2t [D][H]  (bf16, n-major/k-contig)
    for (int l = 0; l < 2; ++l) {
        k_castT<<<(D * H + 255) / 256, 256, 0, stream>>>(W1 + (size_t)l * D * H,
                                                         W1t + (size_t)l * D * H, D, H);
        k_castT<<<(D * H + 255) / 256, 256, 0, stream>>>(W2 + (size_t)l * D * H,
                                                         W2t + (size_t)l * D * H, H, D);
    }
    k_hist<<<(E + 255) / 256, 256, 0, stream>>>(dst, deg, E);
    k_scan<<<1, 1024, 0, stream>>>(deg, row_off, cursor, N);
    k_scatter<<<(E + 255) / 256, 256, 0, stream>>>(src, dst, eattr, cursor, col_src, ea_perm, E);

    for (int l = 0; l < 2; ++l) {
        hipMemsetAsync(stats, 0, (size_t)2 * D * 4, stream);
        k_bn_stats<<<256, 256, 0, stream>>>(h, stats, N);
        k_bn_final<<<1, 128, 0, stream>>>(stats, bn_gamma + l * D, bn_beta + l * D, scl, N);
        k_agg<<<N, 128, 0, stream>>>(h, scl, ea_perm, col_src, row_off, We, be, t_all, l, ob, N);
        dim3 g1(MPAD / 128, H / 128);
        k_gemm_mfma<0><<<g1, 256, 0, stream>>>(ob, W1t + (size_t)l * D * H, b1 + l * H, z1,
                                               MPAD, H, D);
        k_ln_relu<<<(N + 3) / 4, 256, 0, stream>>>(z1, z1r, ln_g + l * H, ln_b + l * H, N);
        dim3 g2(MPAD / 128, D / 128);
        k_gemm_mfma<1><<<g2, 256, 0, stream>>>(z1r, W2t + (size_t)l * D * H, b2 + l * D, h,
                                               MPAD, D, H);
    }
    k_dot<<<(E + 3) / 4, 256, 0, stream>>>(h, src, dst, out, E);
}

// Round 3
// 543.220 us; speedup vs baseline: 2.0986x; 1.3664x over previous
//
#include <hip/hip_runtime.h>
#include <hip/hip_bf16.h>
#include <math.h>

#define NN 50000
#define NE 600000
#define MPAD 50048      // 782*64 = 391*128
#define DIM 128
#define HID 256
#define EPS_MSG 1e-7f
#define EPS_NORM 1e-5f

typedef __attribute__((ext_vector_type(8))) short short8v;
typedef __attribute__((ext_vector_type(4))) float f32x4;

__device__ inline ushort f2bf(float f) {
    union { float f; unsigned u; } v; v.f = f;
    unsigned r = v.u + 0x7FFF + ((v.u >> 16) & 1);
    return (ushort)(r >> 16);
}
__device__ inline float bf2f(ushort u) {
    union { unsigned u; float f; } v; v.u = (unsigned)u << 16; return v.f;
}

// ---------------- x scalar stats: Sx, Sxx ----------------
__global__ void k_xstats(const float* __restrict__ x, float* __restrict__ xs, int n) {
    int lane = threadIdx.x & 63;
    float s = 0.f, q = 0.f;
    for (int i = blockIdx.x * blockDim.x + threadIdx.x; i < n; i += gridDim.x * blockDim.x) {
        float v = x[i];
        s += v; q += v * v;
    }
    #pragma unroll
    for (int off = 32; off >= 1; off >>= 1) {
        s += __shfl_xor(s, off, 64);
        q += __shfl_xor(q, off, 64);
    }
    if (lane == 0) { atomicAdd(&xs[0], s); atomicAdd(&xs[1], q); }
}

// ---------------- layer-0 BN params, closed form (h = x*Wn + bnb is rank-1) -------------
__global__ void k_prep0(const float* __restrict__ xs, const float* __restrict__ Wn,
                        const float* __restrict__ bnb, const float* __restrict__ gamma,
                        const float* __restrict__ beta, float* __restrict__ scl) {
    int d = threadIdx.x;  // 128
    float mx = xs[0] / (float)NN;
    float vx = xs[1] / (float)NN - mx * mx;
    float w = Wn[d], b = bnb[d];
    float mu = mx * w + b;
    float var = vx * w * w;
    float rstd = rsqrtf(var + EPS_NORM);
    float sc = rstd * gamma[d];
    float of = beta[d] - mu * sc;
    scl[2 * DIM + d] = w * sc;            // c1
    scl[3 * DIM + d] = fmaf(b, sc, of);   // c0
}

// ---------------- layer-0 hn (bf16): relu(x[n]*c1[d] + c0[d]) ----------------
__global__ void k_hn0(const float* __restrict__ x, const float* __restrict__ scl,
                      ushort* __restrict__ hn, int total4) {
    int i = blockIdx.x * blockDim.x + threadIdx.x;
    if (i >= total4) return;
    int d4 = (i & 31) * 4;
    int n = i >> 5;
    float xv = x[n];
    float4 c1 = *(const float4*)(scl + 2 * DIM + d4);
    float4 c0 = *(const float4*)(scl + 3 * DIM + d4);
    ushort4 o;
    o.x = f2bf(fmaxf(fmaf(xv, c1.x, c0.x), 0.f));
    o.y = f2bf(fmaxf(fmaf(xv, c1.y, c0.y), 0.f));
    o.z = f2bf(fmaxf(fmaf(xv, c1.z, c0.z), 0.f));
    o.w = f2bf(fmaxf(fmaf(xv, c1.w, c0.w), 0.f));
    *(ushort4*)(hn + (size_t)n * DIM + d4) = o;
}

// ---------------- weight cast + transpose: in[R][C] fp32 -> out[C][R] bf16 ----------------
__global__ void k_castT(const float* __restrict__ in, ushort* __restrict__ out, int R, int C) {
    int i = blockIdx.x * blockDim.x + threadIdx.x;
    if (i >= R * C) return;
    int r = i / C, c = i - r * C;
    out[(size_t)c * R + r] = f2bf(in[i]);
}

// ---------------- CSR build ----------------
__global__ void k_hist(const int* __restrict__ dst, int* __restrict__ deg, int E) {
    int i = blockIdx.x * blockDim.x + threadIdx.x;
    if (i < E) atomicAdd(&deg[dst[i]], 1);
}

__global__ __launch_bounds__(1024) void k_scan(const int* __restrict__ deg,
                                               int* __restrict__ row_off,
                                               int* __restrict__ cursor, int n) {
    __shared__ int wsum[16];
    __shared__ int carry;
    if (threadIdx.x == 0) carry = 0;
    __syncthreads();
    int lane = threadIdx.x & 63;
    int wid = threadIdx.x >> 6;
    for (int base = 0; base < n; base += 1024) {
        int i = base + (int)threadIdx.x;
        int v = (i < n) ? deg[i] : 0;
        int x = v;
        #pragma unroll
        for (int off = 1; off < 64; off <<= 1) {
            int y = __shfl_up(x, off, 64);
            if (lane >= off) x += y;
        }
        if (lane == 63) wsum[wid] = x;
        __syncthreads();
        if (wid == 0 && lane < 16) {
            int w = wsum[lane];
            #pragma unroll
            for (int off = 1; off < 16; off <<= 1) {
                int y = __shfl_up(w, off, 64);
                if (lane >= off) w += y;
            }
            wsum[lane] = w;
        }
        __syncthreads();
        int prev = (wid == 0) ? 0 : wsum[wid - 1];
        int excl = carry + prev + (x - v);
        if (i < n) { row_off[i] = excl; cursor[i] = excl; }
        int chunk_total = wsum[15];
        __syncthreads();
        if (threadIdx.x == 0) carry += chunk_total;
        __syncthreads();
    }
    if (threadIdx.x == 0) row_off[n] = carry;
}

__global__ void k_scatter(const int* __restrict__ src, const int* __restrict__ dst,
                          const float* __restrict__ eattr, int* __restrict__ cursor,
                          int* __restrict__ col_src, float* __restrict__ ea_perm,
                          int* __restrict__ eid, int E) {
    int i = blockIdx.x * blockDim.x + threadIdx.x;
    if (i >= E) return;
    int d = dst[i];
    int pos = atomicAdd(&cursor[d], 1);
    col_src[pos] = src[i];
    ea_perm[pos] = eattr[i];
    eid[pos] = i;
}

// ---------------- BN finalize (layer 1) ----------------
__global__ void k_bn_final(const float* __restrict__ stats, const float* __restrict__ gamma,
                           const float* __restrict__ beta, float* __restrict__ scl) {
    int d = threadIdx.x;  // 128
    float mu = stats[d] / (float)NN;
    float var = stats[DIM + d] / (float)NN - mu * mu;
    float rstd = rsqrtf(var + EPS_NORM);
    float sc = rstd * gamma[d];
    scl[d] = sc;
    scl[DIM + d] = beta[d] - mu * sc;
}

// ---------------- BN apply + ReLU -> bf16 hn ----------------
__global__ void k_bn_relu(const float* __restrict__ h, const float* __restrict__ scl,
                          ushort* __restrict__ hn, int total4) {
    int i = blockIdx.x * blockDim.x + threadIdx.x;
    if (i >= total4) return;
    int d4 = (i & 31) * 4;
    int n = i >> 5;
    float4 v = *(const float4*)(h + (size_t)n * DIM + d4);
    float4 sc = *(const float4*)(scl + d4);
    float4 of = *(const float4*)(scl + DIM + d4);
    ushort4 o;
    o.x = f2bf(fmaxf(fmaf(v.x, sc.x, of.x), 0.f));
    o.y = f2bf(fmaxf(fmaf(v.y, sc.y, of.y), 0.f));
    o.z = f2bf(fmaxf(fmaf(v.z, sc.z, of.z), 0.f));
    o.w = f2bf(fmaxf(fmaf(v.w, sc.w, of.w), 0.f));
    *(ushort4*)(hn + (size_t)n * DIM + d4) = o;
}

// ------------- GENConv softmax aggregation: wave per node, lane = 2 channels -------------
__global__ __launch_bounds__(256) void k_agg(const ushort* __restrict__ hn,
                                             const float* __restrict__ ea_perm,
                                             const int* __restrict__ col_src,
                                             const int* __restrict__ row_off,
                                             const float* __restrict__ We,
                                             const float* __restrict__ be,
                                             const float* __restrict__ t_all, int l,
                                             ushort* __restrict__ ob, int N) {
    int n = blockIdx.x * 4 + (threadIdx.x >> 6);
    if (n >= N) return;
    int lane = threadIdx.x & 63;
    int d0 = lane * 2;
    float2 we = *(const float2*)(We + d0);
    float2 bd = *(const float2*)(be + d0);
    float t = t_all[l];
    int p0 = row_off[n], p1 = row_off[n + 1];
    int deg = p1 - p0;

    // coalesced per-lane edge metadata, broadcast via shfl
    int mp = p0 + lane;
    int s_l = (mp < p1) ? col_src[mp] : 0;
    float ea_l = (mp < p1) ? ea_perm[mp] : 0.f;

    float den0 = 0.f, num0 = 0.f, den1 = 0.f, num1 = 0.f;
    int kmax = deg < 64 ? deg : 64;
    for (int k = 0; k < kmax; ++k) {
        int s = __shfl(s_l, k, 64);
        float ea = __shfl(ea_l, k, 64);
        uint hv = *(const uint*)(hn + (size_t)s * DIM + d0);
        float m0 = fmaxf(bf2f((ushort)hv) + fmaf(ea, we.x, bd.x), 0.f) + EPS_MSG;
        float m1 = fmaxf(bf2f((ushort)(hv >> 16)) + fmaf(ea, we.y, bd.y), 0.f) + EPS_MSG;
        float x0 = __expf(m0 * t), x1 = __expf(m1 * t);
        den0 += x0; num0 += m0 * x0;
        den1 += x1; num1 += m1 * x1;
    }
    for (int p = p0 + 64; p < p1; ++p) {  // rare: deg > 64
        int s = col_src[p];
        float ea = ea_perm[p];
        uint hv = *(const uint*)(hn + (size_t)s * DIM + d0);
        float m0 = fmaxf(bf2f((ushort)hv) + fmaf(ea, we.x, bd.x), 0.f) + EPS_MSG;
        float m1 = fmaxf(bf2f((ushort)(hv >> 16)) + fmaf(ea, we.y, bd.y), 0.f) + EPS_MSG;
        float x0 = __expf(m0 * t), x1 = __expf(m1 * t);
        den0 += x0; num0 += m0 * x0;
        den1 += x1; num1 += m1 * x1;
    }
    uint hr = *(const uint*)(hn + (size_t)n * DIM + d0);
    float a0 = (deg > 0) ? num0 / (den0 + 1e-16f) : 0.f;
    float a1 = (deg > 0) ? num1 / (den1 + 1e-16f) : 0.f;
    uint o = (uint)f2bf(a0 + bf2f((ushort)hr)) |
             ((uint)f2bf(a1 + bf2f((ushort)(hr >> 16))) << 16);
    *(uint*)(ob + (size_t)n * DIM + d0) = o;
}

// -------- GEMM1 + bias + LayerNorm + ReLU -> bf16.  BM=64, BN=HID=256, K=DIM=128. -------
// 256 threads = 4 waves; wave w: rows 0..63, cols w*64..w*64+63. B read direct (L2-hot).
__global__ __launch_bounds__(256) void k_gemm_ln(const ushort* __restrict__ A,
                                                 const ushort* __restrict__ Bt,
                                                 const float* __restrict__ b1,
                                                 const float* __restrict__ g,
                                                 const float* __restrict__ bv,
                                                 ushort* __restrict__ Z) {
    constexpr int LDT = 136;
    __shared__ ushort As[64 * LDT];
    __shared__ float red_s[4][64];
    __shared__ float red_q[4][64];
    __shared__ float murs[2][64];
    const int tid = threadIdx.x;
    const int lane = tid & 63;
    const int wid = tid >> 6;
    const int row0 = blockIdx.x * 64;
    const int wc = wid * 64;
    const int l15 = lane & 15;
    const int lq = lane >> 4;

    #pragma unroll
    for (int i = 0; i < 4; ++i) {
        int idx = tid + i * 256;       // 0..1023
        int r = idx >> 4;
        int c8 = (idx & 15) * 8;
        *(float4*)(As + r * LDT + c8) = *(const float4*)(A + (size_t)(row0 + r) * DIM + c8);
    }
    __syncthreads();

    f32x4 acc[4][4] = {};
    #pragma unroll
    for (int ks = 0; ks < 4; ++ks) {
        int kk = ks * 32 + lq * 8;
        short8v bfr[4], afr[4];
        #pragma unroll
        for (int f = 0; f < 4; ++f)
            bfr[f] = *(const short8v*)(Bt + (size_t)(wc + f * 16 + l15) * DIM + kk);
        #pragma unroll
        for (int f = 0; f < 4; ++f)
            afr[f] = *(const short8v*)(As + (f * 16 + l15) * LDT + kk);
        #pragma unroll
        for (int mi = 0; mi < 4; ++mi)
            #pragma unroll
            for (int ni = 0; ni < 4; ++ni)
                acc[mi][ni] = __builtin_amdgcn_mfma_f32_16x16x32_bf16(
                    afr[mi], bfr[ni], acc[mi][ni], 0, 0, 0);
    }

    // + bias, then row partials over this wave's 64 cols
    float bb[4], gg[4], bb2[4];
    #pragma unroll
    for (int ni = 0; ni < 4; ++ni) {
        int col = wc + ni * 16 + l15;
        bb[ni] = b1[col]; gg[ni] = g[col]; bb2[ni] = bv[col];
    }
    #pragma unroll
    for (int mi = 0; mi < 4; ++mi) {
        #pragma unroll
        for (int j = 0; j < 4; ++j) {
            float s = 0.f, q = 0.f;
            #pragma unroll
            for (int ni = 0; ni < 4; ++ni) {
                float v = acc[mi][ni][j] + bb[ni];
                acc[mi][ni][j] = v;
                s += v; q += v * v;
            }
            #pragma unroll
            for (int off = 1; off <= 8; off <<= 1) {
                s += __shfl_xor(s, off, 64);
                q += __shfl_xor(q, off, 64);
            }
            if (l15 == 0) {
                int row = mi * 16 + lq * 4 + j;
                red_s[wid][row] = s;
                red_q[wid][row] = q;
            }
        }
    }
    __syncthreads();
    if (tid < 64) {
        float s = red_s[0][tid] + red_s[1][tid] + red_s[2][tid] + red_s[3][tid];
        float q = red_q[0][tid] + red_q[1][tid] + red_q[2][tid] + red_q[3][tid];
        float mu = s * (1.f / HID);
        float var = q * (1.f / HID) - mu * mu;
        murs[0][tid] = mu;
        murs[1][tid] = rsqrtf(var + EPS_NORM);
    }
    __syncthreads();
    #pragma unroll
    for (int mi = 0; mi < 4; ++mi) {
        #pragma unroll
        for (int j = 0; j < 4; ++j) {
            int row = mi * 16 + lq * 4 + j;
            float mu = murs[0][row], rs = murs[1][row];
            #pragma unroll
            for (int ni = 0; ni < 4; ++ni) {
                float v = fmaxf(fmaf((acc[mi][ni][j] - mu) * rs, gg[ni], bb2[ni]), 0.f);
                Z[(size_t)(row0 + row) * HID + wc + ni * 16 + l15] = f2bf(v);
            }
        }
    }
}

// -------- GEMM2: h = z1r @ W2 + b2 + base; optional per-column stats. BM=BN=128, K=256. --
// FIRST: base = x*Wn + bnb (layer 0, no h read). else base = h (residual read).
template <int FIRST, int STATS>
__global__ __launch_bounds__(256, 2) void k_gemm2(const ushort* __restrict__ A,
                                                  const ushort* __restrict__ Bt,
                                                  const float* __restrict__ b2,
                                                  const float* __restrict__ x,
                                                  const float* __restrict__ Wn,
                                                  const float* __restrict__ bnb,
                                                  float* __restrict__ C,
                                                  float* __restrict__ stats) {
    constexpr int LDT = 136;
    constexpr int K = HID;
    __shared__ ushort As[128 * LDT];
    __shared__ ushort Bs[128 * LDT];
    const int tid = threadIdx.x;
    const int row0 = blockIdx.x * 128;
    const int wid = tid >> 6;
    const int lane = tid & 63;
    const int wr = (wid >> 1) * 64;
    const int wc = (wid & 1) * 64;
    const int l15 = lane & 15;
    const int lq = lane >> 4;
    f32x4 acc[4][4] = {};

    for (int k0 = 0; k0 < K; k0 += 128) {
        float4 va[8], vb[8];
        #pragma unroll
        for (int i = 0; i < 8; ++i) {
            int idx = tid + i * 256;
            int r = idx >> 4;
            int c8 = (idx & 15) * 8;
            va[i] = *(const float4*)(A + (size_t)(row0 + r) * K + k0 + c8);
            vb[i] = *(const float4*)(Bt + (size_t)r * K + k0 + c8);
        }
        if (k0) __syncthreads();
        #pragma unroll
        for (int i = 0; i < 8; ++i) {
            int idx = tid + i * 256;
            int r = idx >> 4;
            int c8 = (idx & 15) * 8;
            *(float4*)(As + r * LDT + c8) = va[i];
            *(float4*)(Bs + r * LDT + c8) = vb[i];
        }
        __syncthreads();
        #pragma unroll
        for (int ks = 0; ks < 4; ++ks) {
            int kk = ks * 32 + lq * 8;
            short8v af[4], bf[4];
            #pragma unroll
            for (int f = 0; f < 4; ++f) {
                af[f] = *(const short8v*)(As + (wr + f * 16 + l15) * LDT + kk);
                bf[f] = *(const short8v*)(Bs + (wc + f * 16 + l15) * LDT + kk);
            }
            #pragma unroll
            for (int mi = 0; mi < 4; ++mi)
                #pragma unroll
                for (int ni = 0; ni < 4; ++ni)
                    acc[mi][ni] = __builtin_amdgcn_mfma_f32_16x16x32_bf16(
                        af[mi], bf[ni], acc[mi][ni], 0, 0, 0);
        }
    }

    float ssum[4] = {0.f, 0.f, 0.f, 0.f};
    float sq[4] = {0.f, 0.f, 0.f, 0.f};
    #pragma unroll
    for (int ni = 0; ni < 4; ++ni) {
        int col = wc + ni * 16 + l15;
        float bvv = b2[col];
        float wnc = FIRST ? Wn[col] : 0.f;
        float bnc = FIRST ? bnb[col] : 0.f;
        #pragma unroll
        for (int mi = 0; mi < 4; ++mi) {
            int rowb = row0 + wr + mi * 16 + lq * 4;
            #pragma unroll
            for (int j = 0; j < 4; ++j) {
                int gr = rowb + j;
                float base;
                if (FIRST) {
                    float xv = (gr < NN) ? x[gr] : 0.f;
                    base = fmaf(xv, wnc, bnc);
                } else {
                    base = C[(size_t)gr * DIM + col];
                }
                float v = acc[mi][ni][j] + bvv + base;
                C[(size_t)gr * DIM + col] = v;
                if (STATS) {
                    bool ok = gr < NN;
                    ssum[ni] += ok ? v : 0.f;
                    sq[ni] += ok ? v * v : 0.f;
                }
            }
        }
    }
    if (STATS) {
        #pragma unroll
        for (int ni = 0; ni < 4; ++ni) {
            float s = ssum[ni], q = sq[ni];
            s += __shfl_xor(s, 16, 64); s += __shfl_xor(s, 32, 64);
            q += __shfl_xor(q, 16, 64); q += __shfl_xor(q, 32, 64);
            if (lq == 0) {
                int col = wc + ni * 16 + l15;
                atomicAdd(&stats[col], s);
                atomicAdd(&stats[DIM + col], q);
            }
        }
    }
}

// ---------------- dot predictor in CSR order: wave per node ----------------
__global__ __launch_bounds__(256) void k_dot(const float* __restrict__ h,
                                             const int* __restrict__ col_src,
                                             const int* __restrict__ eid,
                                             const int* __restrict__ row_off,
                                             float* __restrict__ out, int N) {
    int n = blockIdx.x * 4 + (threadIdx.x >> 6);
    if (n >= N) return;
    int lane = threadIdx.x & 63;
    float2 hd = ((const float2*)(h + (size_t)n * DIM))[lane];
    int p0 = row_off[n], p1 = row_off[n + 1];
    int deg = p1 - p0;
    int mp = p0 + lane;
    int s_l = (mp < p1) ? col_src[mp] : 0;
    int e_l = (mp < p1) ? eid[mp] : 0;
    int kmax = deg < 64 ? deg : 64;
    for (int k = 0; k < kmax; ++k) {
        int s = __shfl(s_l, k, 64);
        int e = __shfl(e_l, k, 64);
        float2 a = ((const float2*)(h + (size_t)s * DIM))[lane];
        float v = a.x * hd.x + a.y * hd.y;
        #pragma unroll
        for (int off = 32; off >= 1; off >>= 1) v += __shfl_xor(v, off, 64);
        if (lane == 0) out[e] = v;
    }
    for (int p = p0 + 64; p < p1; ++p) {  // rare: deg > 64
        int s = col_src[p];
        int e = eid[p];
        float2 a = ((const float2*)(h + (size_t)s * DIM))[lane];
        float v = a.x * hd.x + a.y * hd.y;
        #pragma unroll
        for (int off = 32; off >= 1; off >>= 1) v += __shfl_xor(v, off, 64);
        if (lane == 0) out[e] = v;
    }
}

extern "C" void kernel_launch(void* const* d_in, const int* in_sizes, int n_in,
                              void* d_out, int out_size, void* d_ws, size_t ws_size,
                              hipStream_t stream) {
    const float* x        = (const float*)d_in[0];
    const int*   ei       = (const int*)d_in[1];
    const float* eattr    = (const float*)d_in[2];
    const float* Wn       = (const float*)d_in[3];
    const float* bnb      = (const float*)d_in[4];
    const float* We       = (const float*)d_in[5];
    const float* be       = (const float*)d_in[6];
    const float* bn_gamma = (const float*)d_in[7];
    const float* bn_beta  = (const float*)d_in[8];
    const float* t_all    = (const float*)d_in[9];
    const float* W1       = (const float*)d_in[10];
    const float* b1       = (const float*)d_in[11];
    const float* ln_g     = (const float*)d_in[12];
    const float* ln_b     = (const float*)d_in[13];
    const float* W2       = (const float*)d_in[14];
    const float* b2       = (const float*)d_in[15];
    float* out = (float*)d_out;

    const int N = NN, E = NE, D = DIM, H = HID;
    const int* src = ei;
    const int* dst = ei + E;

    char* ws = (char*)d_ws;
    auto alloc = [&](size_t bytes) {
        char* p = ws;
        ws += (bytes + 255) & ~(size_t)255;
        return p;
    };
    float*  h       = (float*)alloc((size_t)MPAD * D * 4);
    ushort* z1r     = (ushort*)alloc((size_t)MPAD * H * 2);
    ushort* ob      = (ushort*)alloc((size_t)MPAD * D * 2);
    ushort* hn      = (ushort*)alloc((size_t)MPAD * D * 2);
    ushort* W1t     = (ushort*)alloc((size_t)2 * D * H * 2);
    ushort* W2t     = (ushort*)alloc((size_t)2 * D * H * 2);
    int*    col_src = (int*)alloc((size_t)E * 4);
    float*  ea_perm = (float*)alloc((size_t)E * 4);
    int*    eid     = (int*)alloc((size_t)E * 4);
    int*    row_off = (int*)alloc((size_t)(N + 1) * 4);
    int*    cursor  = (int*)alloc((size_t)N * 4);
    int*    deg     = (int*)alloc((size_t)N * 4);
    float*  stats   = (float*)alloc((size_t)2 * D * 4);
    float*  scl     = (float*)alloc((size_t)4 * D * 4);
    float*  xs      = (float*)alloc((size_t)2 * 4);

    hipMemsetAsync(deg, 0, (size_t)N * 4, stream);
    hipMemsetAsync(xs, 0, 8, stream);
    hipMemsetAsync(stats, 0, (size_t)2 * D * 4, stream);

    k_xstats<<<64, 256, 0, stream>>>(x, xs, N);
    k_prep0<<<1, 128, 0, stream>>>(xs, Wn, bnb, bn_gamma, bn_beta, scl);
    k_hn0<<<(N * 32 + 255) / 256, 256, 0, stream>>>(x, scl, hn, N * 32);
    for (int l = 0; l < 2; ++l) {
        k_castT<<<(D * H + 255) / 256, 256, 0, stream>>>(W1 + (size_t)l * D * H,
                                                         W1t + (size_t)l * D * H, D, H);
        k_castT<<<(D * H + 255) / 256, 256, 0, stream>>>(W2 + (size_t)l * D * H,
                                                         W2t + (size_t)l * D * H, H, D);
    }
    k_hist<<<(E + 255) / 256, 256, 0, stream>>>(dst, deg, E);
    k_scan<<<1, 1024, 0, stream>>>(deg, row_off, cursor, N);
    k_scatter<<<(E + 255) / 256, 256, 0, stream>>>(src, dst, eattr, cursor,
                                                   col_src, ea_perm, eid, E);

    // ---- layer 0 ----
    k_agg<<<(N + 3) / 4, 256, 0, stream>>>(hn, ea_perm, col_src, row_off, We, be,
                                           t_all, 0, ob, N);
    k_gemm_ln<<<MPAD / 64, 256, 0, stream>>>(ob, W1t, b1, ln_g, ln_b, z1r);
    k_gemm2<1, 1><<<MPAD / 128, 256, 0, stream>>>(z1r, W2t, b2, x, Wn, bnb, h, stats);
    k_bn_final<<<1, 128, 0, stream>>>(stats, bn_gamma + D, bn_beta + D, scl);
    k_bn_relu<<<(N * 32 + 255) / 256, 256, 0, stream>>>(h, scl, hn, N * 32);

    // ---- layer 1 ----
    k_agg<<<(N + 3) / 4, 256, 0, stream>>>(hn, ea_perm, col_src, row_off, We, be,
                                           t_all, 1, ob, N);
    k_gemm_ln<<<MPAD / 64, 256, 0, stream>>>(ob, W1t + (size_t)D * H, b1 + H,
                                             ln_g + H, ln_b + H, z1r);
    k_gemm2<0, 0><<<MPAD / 128, 256, 0, stream>>>(z1r, W2t + (size_t)D * H, b2 + D,
                                                  x, Wn, bnb, h, stats);

    k_dot<<<(N + 3) / 4, 256, 0, stream>>>(h, col_src, eid, row_off, out, N);
}

// Round 4
// 445.382 us; speedup vs baseline: 2.5596x; 1.2197x over previous
//
#include <hip/hip_runtime.h>
#include <hip/hip_bf16.h>
#include <math.h>

#define NN 50000
#define NE 600000
#define MPAD 50048      // 782*64 = 391*128
#define DIM 128
#define HID 256
#define EPS_MSG 1e-7f
#define EPS_NORM 1e-5f

typedef __attribute__((ext_vector_type(8))) short short8v;
typedef __attribute__((ext_vector_type(8))) unsigned short ushort8v;
typedef __attribute__((ext_vector_type(4))) float f32x4;

__device__ inline ushort f2bf(float f) {
    union { float f; unsigned u; } v; v.f = f;
    unsigned r = v.u + 0x7FFF + ((v.u >> 16) & 1);
    return (ushort)(r >> 16);
}
__device__ inline float bf2f(ushort u) {
    union { unsigned u; float f; } v; v.u = (unsigned)u << 16; return v.f;
}

// ---------------- x scalar stats: Sx, Sxx ----------------
__global__ void k_xstats(const float* __restrict__ x, float* __restrict__ xs, int n) {
    int lane = threadIdx.x & 63;
    float s = 0.f, q = 0.f;
    for (int i = blockIdx.x * blockDim.x + threadIdx.x; i < n; i += gridDim.x * blockDim.x) {
        float v = x[i];
        s += v; q += v * v;
    }
    #pragma unroll
    for (int off = 32; off >= 1; off >>= 1) {
        s += __shfl_xor(s, off, 64);
        q += __shfl_xor(q, off, 64);
    }
    if (lane == 0) { atomicAdd(&xs[0], s); atomicAdd(&xs[1], q); }
}

// ------- layer-0 hn (bf16): BN params in closed form (h = x*Wn + bnb is rank-1) -------
__global__ void k_hn0(const float* __restrict__ x, const float* __restrict__ xs,
                      const float* __restrict__ Wn, const float* __restrict__ bnb,
                      const float* __restrict__ gamma, const float* __restrict__ beta,
                      ushort* __restrict__ hn, int total4) {
    int i = blockIdx.x * blockDim.x + threadIdx.x;
    if (i >= total4) return;
    int d4 = (i & 31) * 4;
    int n = i >> 5;
    float mx = xs[0] * (1.f / NN);
    float vx = xs[1] * (1.f / NN) - mx * mx;
    float xv = x[n];
    float4 w = *(const float4*)(Wn + d4);
    float4 b = *(const float4*)(bnb + d4);
    float4 g = *(const float4*)(gamma + d4);
    float4 bt = *(const float4*)(beta + d4);
    ushort4 o;
    {
        float mu = fmaf(mx, w.x, b.x), sc = rsqrtf(vx * w.x * w.x + EPS_NORM) * g.x;
        o.x = f2bf(fmaxf(fmaf(fmaf(xv, w.x, b.x) - mu, sc, bt.x), 0.f));
    }
    {
        float mu = fmaf(mx, w.y, b.y), sc = rsqrtf(vx * w.y * w.y + EPS_NORM) * g.y;
        o.y = f2bf(fmaxf(fmaf(fmaf(xv, w.y, b.y) - mu, sc, bt.y), 0.f));
    }
    {
        float mu = fmaf(mx, w.z, b.z), sc = rsqrtf(vx * w.z * w.z + EPS_NORM) * g.z;
        o.z = f2bf(fmaxf(fmaf(fmaf(xv, w.z, b.z) - mu, sc, bt.z), 0.f));
    }
    {
        float mu = fmaf(mx, w.w, b.w), sc = rsqrtf(vx * w.w * w.w + EPS_NORM) * g.w;
        o.w = f2bf(fmaxf(fmaf(fmaf(xv, w.w, b.w) - mu, sc, bt.w), 0.f));
    }
    *(ushort4*)(hn + (size_t)n * DIM + d4) = o;
}

// ------- all weight casts+transposes in one kernel: W1 [D][H]->[H][D], W2 [H][D]->[D][H] ---
__global__ void k_castAll(const float* __restrict__ W1, const float* __restrict__ W2,
                          ushort* __restrict__ W1t, ushort* __restrict__ W2t) {
    const int chunk = DIM * HID;
    int i = blockIdx.x * blockDim.x + threadIdx.x;
    if (i >= 4 * chunk) return;
    int w = i / chunk;
    int j = i - w * chunk;
    if (w < 2) {
        int r = j / HID, c = j - r * HID;
        W1t[(size_t)w * chunk + (size_t)c * DIM + r] = f2bf(W1[(size_t)w * chunk + j]);
    } else {
        int l = w - 2;
        int r = j / DIM, c = j - r * DIM;
        W2t[(size_t)l * chunk + (size_t)c * HID + r] = f2bf(W2[(size_t)l * chunk + j]);
    }
}

// ---------------- CSR build ----------------
__global__ void k_hist(const int* __restrict__ dst, int* __restrict__ deg, int E) {
    int i = blockIdx.x * blockDim.x + threadIdx.x;
    if (i < E) atomicAdd(&deg[dst[i]], 1);
}

__global__ __launch_bounds__(1024) void k_scan(const int* __restrict__ deg,
                                               int* __restrict__ row_off,
                                               int* __restrict__ cursor, int n) {
    __shared__ int wsum[16];
    __shared__ int carry;
    if (threadIdx.x == 0) carry = 0;
    __syncthreads();
    int lane = threadIdx.x & 63;
    int wid = threadIdx.x >> 6;
    for (int base = 0; base < n; base += 1024) {
        int i = base + (int)threadIdx.x;
        int v = (i < n) ? deg[i] : 0;
        int x = v;
        #pragma unroll
        for (int off = 1; off < 64; off <<= 1) {
            int y = __shfl_up(x, off, 64);
            if (lane >= off) x += y;
        }
        if (lane == 63) wsum[wid] = x;
        __syncthreads();
        if (wid == 0 && lane < 16) {
            int w = wsum[lane];
            #pragma unroll
            for (int off = 1; off < 16; off <<= 1) {
                int y = __shfl_up(w, off, 64);
                if (lane >= off) w += y;
            }
            wsum[lane] = w;
        }
        __syncthreads();
        int prev = (wid == 0) ? 0 : wsum[wid - 1];
        int excl = carry + prev + (x - v);
        if (i < n) { row_off[i] = excl; cursor[i] = excl; }
        int chunk_total = wsum[15];
        __syncthreads();
        if (threadIdx.x == 0) carry += chunk_total;
        __syncthreads();
    }
    if (threadIdx.x == 0) row_off[n] = carry;
}

__global__ void k_scatter(const int* __restrict__ src, const int* __restrict__ dst,
                          const float* __restrict__ eattr, int* __restrict__ cursor,
                          int* __restrict__ col_src, float* __restrict__ ea_perm,
                          int* __restrict__ eid, int E) {
    int i = blockIdx.x * blockDim.x + threadIdx.x;
    if (i >= E) return;
    int d = dst[i];
    int pos = atomicAdd(&cursor[d], 1);
    col_src[pos] = src[i];
    ea_perm[pos] = eattr[i];
    eid[pos] = i;
}

// ------- BN apply + ReLU -> bf16 hn (finalize fused: per-thread from raw stats) -------
__global__ void k_bn_relu(const float* __restrict__ h, const float* __restrict__ stats,
                          const float* __restrict__ gamma, const float* __restrict__ beta,
                          ushort* __restrict__ hn, int total4) {
    int i = blockIdx.x * blockDim.x + threadIdx.x;
    if (i >= total4) return;
    int d4 = (i & 31) * 4;
    int n = i >> 5;
    float4 v = *(const float4*)(h + (size_t)n * DIM + d4);
    float4 s = *(const float4*)(stats + d4);
    float4 q = *(const float4*)(stats + DIM + d4);
    float4 g = *(const float4*)(gamma + d4);
    float4 bt = *(const float4*)(beta + d4);
    ushort4 o;
    {
        float mu = s.x * (1.f / NN), var = q.x * (1.f / NN) - mu * mu;
        float sc = rsqrtf(var + EPS_NORM) * g.x;
        o.x = f2bf(fmaxf(fmaf(v.x - mu, sc, bt.x), 0.f));
    }
    {
        float mu = s.y * (1.f / NN), var = q.y * (1.f / NN) - mu * mu;
        float sc = rsqrtf(var + EPS_NORM) * g.y;
        o.y = f2bf(fmaxf(fmaf(v.y - mu, sc, bt.y), 0.f));
    }
    {
        float mu = s.z * (1.f / NN), var = q.z * (1.f / NN) - mu * mu;
        float sc = rsqrtf(var + EPS_NORM) * g.z;
        o.z = f2bf(fmaxf(fmaf(v.z - mu, sc, bt.z), 0.f));
    }
    {
        float mu = s.w * (1.f / NN), var = q.w * (1.f / NN) - mu * mu;
        float sc = rsqrtf(var + EPS_NORM) * g.w;
        o.w = f2bf(fmaxf(fmaf(v.w - mu, sc, bt.w), 0.f));
    }
    *(ushort4*)(hn + (size_t)n * DIM + d4) = o;
}

// ------- GENConv softmax aggregation: wave per node, lane = 2 channels, unroll-4 -------
__global__ __launch_bounds__(256) void k_agg(const ushort* __restrict__ hn,
                                             const float* __restrict__ ea_perm,
                                             const int* __restrict__ col_src,
                                             const int* __restrict__ row_off,
                                             const float* __restrict__ We,
                                             const float* __restrict__ be,
                                             const float* __restrict__ t_all, int l,
                                             ushort* __restrict__ ob, int N) {
    int n = blockIdx.x * 4 + (threadIdx.x >> 6);
    if (n >= N) return;
    int lane = threadIdx.x & 63;
    int d0 = lane * 2;
    float2 we = *(const float2*)(We + d0);
    float2 bd = *(const float2*)(be + d0);
    float t = t_all[l];
    int p0 = row_off[n], p1 = row_off[n + 1];
    int deg = p1 - p0;

    int mp = p0 + lane;
    int s_l = (mp < p1) ? col_src[mp] : 0;
    float ea_l = (mp < p1) ? ea_perm[mp] : 0.f;

    float den0 = 0.f, num0 = 0.f, den1 = 0.f, num1 = 0.f;
    int kmax = deg < 64 ? deg : 64;
    int k = 0;
    for (; k + 4 <= kmax; k += 4) {
        int sA = __shfl(s_l, k, 64), sB = __shfl(s_l, k + 1, 64);
        int sC = __shfl(s_l, k + 2, 64), sD = __shfl(s_l, k + 3, 64);
        float eA = __shfl(ea_l, k, 64), eB = __shfl(ea_l, k + 1, 64);
        float eC = __shfl(ea_l, k + 2, 64), eD = __shfl(ea_l, k + 3, 64);
        uint hA = *(const uint*)(hn + (size_t)sA * DIM + d0);
        uint hB = *(const uint*)(hn + (size_t)sB * DIM + d0);
        uint hC = *(const uint*)(hn + (size_t)sC * DIM + d0);
        uint hD = *(const uint*)(hn + (size_t)sD * DIM + d0);
        {
            float m0 = fmaxf(bf2f((ushort)hA) + fmaf(eA, we.x, bd.x), 0.f) + EPS_MSG;
            float m1 = fmaxf(bf2f((ushort)(hA >> 16)) + fmaf(eA, we.y, bd.y), 0.f) + EPS_MSG;
            float x0 = __expf(m0 * t), x1 = __expf(m1 * t);
            den0 += x0; num0 += m0 * x0; den1 += x1; num1 += m1 * x1;
        }
        {
            float m0 = fmaxf(bf2f((ushort)hB) + fmaf(eB, we.x, bd.x), 0.f) + EPS_MSG;
            float m1 = fmaxf(bf2f((ushort)(hB >> 16)) + fmaf(eB, we.y, bd.y), 0.f) + EPS_MSG;
            float x0 = __expf(m0 * t), x1 = __expf(m1 * t);
            den0 += x0; num0 += m0 * x0; den1 += x1; num1 += m1 * x1;
        }
        {
            float m0 = fmaxf(bf2f((ushort)hC) + fmaf(eC, we.x, bd.x), 0.f) + EPS_MSG;
            float m1 = fmaxf(bf2f((ushort)(hC >> 16)) + fmaf(eC, we.y, bd.y), 0.f) + EPS_MSG;
            float x0 = __expf(m0 * t), x1 = __expf(m1 * t);
            den0 += x0; num0 += m0 * x0; den1 += x1; num1 += m1 * x1;
        }
        {
            float m0 = fmaxf(bf2f((ushort)hD) + fmaf(eD, we.x, bd.x), 0.f) + EPS_MSG;
            float m1 = fmaxf(bf2f((ushort)(hD >> 16)) + fmaf(eD, we.y, bd.y), 0.f) + EPS_MSG;
            float x0 = __expf(m0 * t), x1 = __expf(m1 * t);
            den0 += x0; num0 += m0 * x0; den1 += x1; num1 += m1 * x1;
        }
    }
    for (; k < kmax; ++k) {
        int s = __shfl(s_l, k, 64);
        float ea = __shfl(ea_l, k, 64);
        uint hv = *(const uint*)(hn + (size_t)s * DIM + d0);
        float m0 = fmaxf(bf2f((ushort)hv) + fmaf(ea, we.x, bd.x), 0.f) + EPS_MSG;
        float m1 = fmaxf(bf2f((ushort)(hv >> 16)) + fmaf(ea, we.y, bd.y), 0.f) + EPS_MSG;
        float x0 = __expf(m0 * t), x1 = __expf(m1 * t);
        den0 += x0; num0 += m0 * x0; den1 += x1; num1 += m1 * x1;
    }
    for (int p = p0 + 64; p < p1; ++p) {  // rare: deg > 64
        int s = col_src[p];
        float ea = ea_perm[p];
        uint hv = *(const uint*)(hn + (size_t)s * DIM + d0);
        float m0 = fmaxf(bf2f((ushort)hv) + fmaf(ea, we.x, bd.x), 0.f) + EPS_MSG;
        float m1 = fmaxf(bf2f((ushort)(hv >> 16)) + fmaf(ea, we.y, bd.y), 0.f) + EPS_MSG;
        float x0 = __expf(m0 * t), x1 = __expf(m1 * t);
        den0 += x0; num0 += m0 * x0; den1 += x1; num1 += m1 * x1;
    }
    uint hr = *(const uint*)(hn + (size_t)n * DIM + d0);
    float a0 = (deg > 0) ? num0 / (den0 + 1e-16f) : 0.f;
    float a1 = (deg > 0) ? num1 / (den1 + 1e-16f) : 0.f;
    uint o = (uint)f2bf(a0 + bf2f((ushort)hr)) |
             ((uint)f2bf(a1 + bf2f((ushort)(hr >> 16))) << 16);
    *(uint*)(ob + (size_t)n * DIM + d0) = o;
}

// -------- GEMM1 + bias + LayerNorm + ReLU -> bf16.  BM=64, BN=HID=256, K=DIM=128. -------
__global__ __launch_bounds__(256) void k_gemm_ln(const ushort* __restrict__ A,
                                                 const ushort* __restrict__ Bt,
                                                 const float* __restrict__ b1,
                                                 const float* __restrict__ g,
                                                 const float* __restrict__ bv,
                                                 ushort* __restrict__ Z) {
    constexpr int LDT = 136;
    __shared__ ushort As[64 * LDT];
    __shared__ float red_s[4][64];
    __shared__ float red_q[4][64];
    __shared__ float murs[2][64];
    const int tid = threadIdx.x;
    const int lane = tid & 63;
    const int wid = tid >> 6;
    const int row0 = blockIdx.x * 64;
    const int wc = wid * 64;
    const int l15 = lane & 15;
    const int lq = lane >> 4;

    #pragma unroll
    for (int i = 0; i < 4; ++i) {
        int idx = tid + i * 256;
        int r = idx >> 4;
        int c8 = (idx & 15) * 8;
        *(float4*)(As + r * LDT + c8) = *(const float4*)(A + (size_t)(row0 + r) * DIM + c8);
    }
    __syncthreads();

    f32x4 acc[4][4] = {};
    #pragma unroll
    for (int ks = 0; ks < 4; ++ks) {
        int kk = ks * 32 + lq * 8;
        short8v bfr[4], afr[4];
        #pragma unroll
        for (int f = 0; f < 4; ++f)
            bfr[f] = *(const short8v*)(Bt + (size_t)(wc + f * 16 + l15) * DIM + kk);
        #pragma unroll
        for (int f = 0; f < 4; ++f)
            afr[f] = *(const short8v*)(As + (f * 16 + l15) * LDT + kk);
        #pragma unroll
        for (int mi = 0; mi < 4; ++mi)
            #pragma unroll
            for (int ni = 0; ni < 4; ++ni)
                acc[mi][ni] = __builtin_amdgcn_mfma_f32_16x16x32_bf16(
                    afr[mi], bfr[ni], acc[mi][ni], 0, 0, 0);
    }

    float bb[4], gg[4], bb2[4];
    #pragma unroll
    for (int ni = 0; ni < 4; ++ni) {
        int col = wc + ni * 16 + l15;
        bb[ni] = b1[col]; gg[ni] = g[col]; bb2[ni] = bv[col];
    }
    #pragma unroll
    for (int mi = 0; mi < 4; ++mi) {
        #pragma unroll
        for (int j = 0; j < 4; ++j) {
            float s = 0.f, q = 0.f;
            #pragma unroll
            for (int ni = 0; ni < 4; ++ni) {
                float v = acc[mi][ni][j] + bb[ni];
                acc[mi][ni][j] = v;
                s += v; q += v * v;
            }
            #pragma unroll
            for (int off = 1; off <= 8; off <<= 1) {
                s += __shfl_xor(s, off, 64);
                q += __shfl_xor(q, off, 64);
            }
            if (l15 == 0) {
                int row = mi * 16 + lq * 4 + j;
                red_s[wid][row] = s;
                red_q[wid][row] = q;
            }
        }
    }
    __syncthreads();
    if (tid < 64) {
        float s = red_s[0][tid] + red_s[1][tid] + red_s[2][tid] + red_s[3][tid];
        float q = red_q[0][tid] + red_q[1][tid] + red_q[2][tid] + red_q[3][tid];
        float mu = s * (1.f / HID);
        float var = q * (1.f / HID) - mu * mu;
        murs[0][tid] = mu;
        murs[1][tid] = rsqrtf(var + EPS_NORM);
    }
    __syncthreads();
    #pragma unroll
    for (int mi = 0; mi < 4; ++mi) {
        #pragma unroll
        for (int j = 0; j < 4; ++j) {
            int row = mi * 16 + lq * 4 + j;
            float mu = murs[0][row], rs = murs[1][row];
            #pragma unroll
            for (int ni = 0; ni < 4; ++ni) {
                float v = fmaxf(fmaf((acc[mi][ni][j] - mu) * rs, gg[ni], bb2[ni]), 0.f);
                Z[(size_t)(row0 + row) * HID + wc + ni * 16 + l15] = f2bf(v);
            }
        }
    }
}

// -------- GEMM2: out = z1r @ W2 + b2 + base. BM=BN=128, K=256. --------
// FIRST: base = x*Wn + bnb (layer 0). else base = C (residual read).
// STATS: accumulate per-column sum/sumsq. OUTB: write bf16 hb instead of fp32 C.
template <int FIRST, int STATS, int OUTB>
__global__ __launch_bounds__(256, 2) void k_gemm2(const ushort* __restrict__ A,
                                                  const ushort* __restrict__ Bt,
                                                  const float* __restrict__ b2,
                                                  const float* __restrict__ x,
                                                  const float* __restrict__ Wn,
                                                  const float* __restrict__ bnb,
                                                  float* __restrict__ C,
                                                  ushort* __restrict__ hb,
                                                  float* __restrict__ stats) {
    constexpr int LDT = 136;
    constexpr int K = HID;
    __shared__ ushort As[128 * LDT];
    __shared__ ushort Bs[128 * LDT];
    const int tid = threadIdx.x;
    const int row0 = blockIdx.x * 128;
    const int wid = tid >> 6;
    const int lane = tid & 63;
    const int wr = (wid >> 1) * 64;
    const int wc = (wid & 1) * 64;
    const int l15 = lane & 15;
    const int lq = lane >> 4;
    f32x4 acc[4][4] = {};

    for (int k0 = 0; k0 < K; k0 += 128) {
        float4 va[8], vb[8];
        #pragma unroll
        for (int i = 0; i < 8; ++i) {
            int idx = tid + i * 256;
            int r = idx >> 4;
            int c8 = (idx & 15) * 8;
            va[i] = *(const float4*)(A + (size_t)(row0 + r) * K + k0 + c8);
            vb[i] = *(const float4*)(Bt + (size_t)r * K + k0 + c8);
        }
        if (k0) __syncthreads();
        #pragma unroll
        for (int i = 0; i < 8; ++i) {
            int idx = tid + i * 256;
            int r = idx >> 4;
            int c8 = (idx & 15) * 8;
            *(float4*)(As + r * LDT + c8) = va[i];
            *(float4*)(Bs + r * LDT + c8) = vb[i];
        }
        __syncthreads();
        #pragma unroll
        for (int ks = 0; ks < 4; ++ks) {
            int kk = ks * 32 + lq * 8;
            short8v af[4], bf[4];
            #pragma unroll
            for (int f = 0; f < 4; ++f) {
                af[f] = *(const short8v*)(As + (wr + f * 16 + l15) * LDT + kk);
                bf[f] = *(const short8v*)(Bs + (wc + f * 16 + l15) * LDT + kk);
            }
            #pragma unroll
            for (int mi = 0; mi < 4; ++mi)
                #pragma unroll
                for (int ni = 0; ni < 4; ++ni)
                    acc[mi][ni] = __builtin_amdgcn_mfma_f32_16x16x32_bf16(
                        af[mi], bf[ni], acc[mi][ni], 0, 0, 0);
        }
    }

    float ssum[4] = {0.f, 0.f, 0.f, 0.f};
    float sq[4] = {0.f, 0.f, 0.f, 0.f};
    #pragma unroll
    for (int ni = 0; ni < 4; ++ni) {
        int col = wc + ni * 16 + l15;
        float bvv = b2[col];
        float wnc = FIRST ? Wn[col] : 0.f;
        float bnc = FIRST ? bnb[col] : 0.f;
        #pragma unroll
        for (int mi = 0; mi < 4; ++mi) {
            int rowb = row0 + wr + mi * 16 + lq * 4;
            #pragma unroll
            for (int j = 0; j < 4; ++j) {
                int gr = rowb + j;
                float base;
                if (FIRST) {
                    float xv = (gr < NN) ? x[gr] : 0.f;
                    base = fmaf(xv, wnc, bnc);
                } else {
                    base = C[(size_t)gr * DIM + col];
                }
                float v = acc[mi][ni][j] + bvv + base;
                if (OUTB) hb[(size_t)gr * DIM + col] = f2bf(v);
                else C[(size_t)gr * DIM + col] = v;
                if (STATS) {
                    bool ok = gr < NN;
                    ssum[ni] += ok ? v : 0.f;
                    sq[ni] += ok ? v * v : 0.f;
                }
            }
        }
    }
    if (STATS) {
        #pragma unroll
        for (int ni = 0; ni < 4; ++ni) {
            float s = ssum[ni], q = sq[ni];
            s += __shfl_xor(s, 16, 64); s += __shfl_xor(s, 32, 64);
            q += __shfl_xor(q, 16, 64); q += __shfl_xor(q, 32, 64);
            if (lq == 0) {
                int col = wc + ni * 16 + l15;
                atomicAdd(&stats[col], s);
                atomicAdd(&stats[DIM + col], q);
            }
        }
    }
}

// ------- dot predictor, CSR order: wave per node, 4 edges/iter (16 lanes x 8 ch) -------
__global__ __launch_bounds__(256) void k_dot(const ushort* __restrict__ hb,
                                             const int* __restrict__ col_src,
                                             const int* __restrict__ eid,
                                             const int* __restrict__ row_off,
                                             float* __restrict__ out, int N) {
    int n = blockIdx.x * 4 + (threadIdx.x >> 6);
    if (n >= N) return;
    int lane = threadIdx.x & 63;
    int sub = lane >> 4;
    int l16 = lane & 15;
    float hd[8];
    {
        ushort8v hv = *(const ushort8v*)(hb + (size_t)n * DIM + l16 * 8);
        #pragma unroll
        for (int j = 0; j < 8; ++j) hd[j] = bf2f(hv[j]);
    }
    int p0 = row_off[n], p1 = row_off[n + 1];
    int deg = p1 - p0;
    int mp = p0 + lane;
    int s_l = (mp < p1) ? col_src[mp] : 0;
    int e_l = (mp < p1) ? eid[mp] : 0;
    int kmax = deg < 64 ? deg : 64;
    for (int k = 0; k < kmax; k += 4) {
        int idx = k + sub;
        bool ok = idx < kmax;
        int s = __shfl(s_l, idx, 64);
        int e = __shfl(e_l, idx, 64);
        ushort8v av = *(const ushort8v*)(hb + (size_t)(ok ? s : n) * DIM + l16 * 8);
        float p = 0.f;
        #pragma unroll
        for (int j = 0; j < 8; ++j) p = fmaf(bf2f(av[j]), hd[j], p);
        p += __shfl_xor(p, 1, 16);
        p += __shfl_xor(p, 2, 16);
        p += __shfl_xor(p, 4, 16);
        p += __shfl_xor(p, 8, 16);
        if (ok && l16 == 0) out[e] = p;
    }
    for (int pb = p0 + 64; pb < p1; pb += 4) {  // rare: deg > 64
        int pe = pb + sub;
        bool ok = pe < p1;
        int s = ok ? col_src[pe] : n;
        int e = ok ? eid[pe] : 0;
        ushort8v av = *(const ushort8v*)(hb + (size_t)s * DIM + l16 * 8);
        float p = 0.f;
        #pragma unroll
        for (int j = 0; j < 8; ++j) p = fmaf(bf2f(av[j]), hd[j], p);
        p += __shfl_xor(p, 1, 16);
        p += __shfl_xor(p, 2, 16);
        p += __shfl_xor(p, 4, 16);
        p += __shfl_xor(p, 8, 16);
        if (ok && l16 == 0) out[e] = p;
    }
}

extern "C" void kernel_launch(void* const* d_in, const int* in_sizes, int n_in,
                              void* d_out, int out_size, void* d_ws, size_t ws_size,
                              hipStream_t stream) {
    const float* x        = (const float*)d_in[0];
    const int*   ei       = (const int*)d_in[1];
    const float* eattr    = (const float*)d_in[2];
    const float* Wn       = (const float*)d_in[3];
    const float* bnb      = (const float*)d_in[4];
    const float* We       = (const float*)d_in[5];
    const float* be       = (const float*)d_in[6];
    const float* bn_gamma = (const float*)d_in[7];
    const float* bn_beta  = (const float*)d_in[8];
    const float* t_all    = (const float*)d_in[9];
    const float* W1       = (const float*)d_in[10];
    const float* b1       = (const float*)d_in[11];
    const float* ln_g     = (const float*)d_in[12];
    const float* ln_b     = (const float*)d_in[13];
    const float* W2       = (const float*)d_in[14];
    const float* b2       = (const float*)d_in[15];
    float* out = (float*)d_out;

    const int N = NN, E = NE, D = DIM, H = HID;
    const int* src = ei;
    const int* dst = ei + E;

    char* ws = (char*)d_ws;
    auto alloc = [&](size_t bytes) {
        char* p = ws;
        ws += (bytes + 255) & ~(size_t)255;
        return p;
    };
    float*  h       = (float*)alloc((size_t)MPAD * D * 4);
    ushort* z1r     = (ushort*)alloc((size_t)MPAD * H * 2);
    ushort* ob      = (ushort*)alloc((size_t)MPAD * D * 2);
    ushort* hn      = (ushort*)alloc((size_t)MPAD * D * 2);
    ushort* hb      = (ushort*)alloc((size_t)MPAD * D * 2);
    ushort* W1t     = (ushort*)alloc((size_t)2 * D * H * 2);
    ushort* W2t     = (ushort*)alloc((size_t)2 * D * H * 2);
    int*    col_src = (int*)alloc((size_t)E * 4);
    float*  ea_perm = (float*)alloc((size_t)E * 4);
    int*    eid     = (int*)alloc((size_t)E * 4);
    int*    row_off = (int*)alloc((size_t)(N + 1) * 4);
    int*    cursor  = (int*)alloc((size_t)N * 4);
    int*    deg     = (int*)alloc((size_t)N * 4);
    float*  stats   = (float*)alloc((size_t)2 * D * 4);   // 1024 B
    float*  xs      = (float*)alloc((size_t)2 * 4);       // adjacent: one memset covers

    hipMemsetAsync(deg, 0, (size_t)N * 4, stream);
    hipMemsetAsync(stats, 0, 1024 + 8, stream);

    k_xstats<<<64, 256, 0, stream>>>(x, xs, N);
    k_castAll<<<(4 * D * H + 255) / 256, 256, 0, stream>>>(W1, W2, W1t, W2t);
    k_hist<<<(E + 255) / 256, 256, 0, stream>>>(dst, deg, E);
    k_scan<<<1, 1024, 0, stream>>>(deg, row_off, cursor, N);
    k_scatter<<<(E + 255) / 256, 256, 0, stream>>>(src, dst, eattr, cursor,
                                                   col_src, ea_perm, eid, E);
    k_hn0<<<(N * 32 + 255) / 256, 256, 0, stream>>>(x, xs, Wn, bnb, bn_gamma, bn_beta,
                                                    hn, N * 32);

    // ---- layer 0 ----
    k_agg<<<(N + 3) / 4, 256, 0, stream>>>(hn, ea_perm, col_src, row_off, We, be,
                                           t_all, 0, ob, N);
    k_gemm_ln<<<MPAD / 64, 256, 0, stream>>>(ob, W1t, b1, ln_g, ln_b, z1r);
    k_gemm2<1, 1, 0><<<MPAD / 128, 256, 0, stream>>>(z1r, W2t, b2, x, Wn, bnb, h, hb, stats);
    k_bn_relu<<<(N * 32 + 255) / 256, 256, 0, stream>>>(h, stats, bn_gamma + D, bn_beta + D,
                                                        hn, N * 32);

    // ---- layer 1 ----
    k_agg<<<(N + 3) / 4, 256, 0, stream>>>(hn, ea_perm, col_src, row_off, We, be,
                                           t_all, 1, ob, N);
    k_gemm_ln<<<MPAD / 64, 256, 0, stream>>>(ob, W1t + (size_t)D * H, b1 + H,
                                             ln_g + H, ln_b + H, z1r);
    k_gemm2<0, 0, 1><<<MPAD / 128, 256, 0, stream>>>(z1r, W2t + (size_t)D * H, b2 + D,
                                                     x, Wn, bnb, h, hb, stats);

    k_dot<<<(N + 3) / 4, 256, 0, stream>>>(hb, col_src, eid, row_off, out, N);
}

// Round 5
// 390.754 us; speedup vs baseline: 2.9174x; 1.1398x over previous
//
#include <hip/hip_runtime.h>
#include <hip/hip_bf16.h>
#include <math.h>

#define NN 50000
#define NE 600000
#define MPAD 50048      // 782*64
#define DIM 128
#define HID 256
#define NB 49           // ceil(NN/1024)
#define EPS_MSG 1e-7f
#define EPS_NORM 1e-5f

typedef __attribute__((ext_vector_type(8))) short short8v;
typedef __attribute__((ext_vector_type(8))) unsigned short ushort8v;
typedef __attribute__((ext_vector_type(4))) float f32x4;

__device__ inline ushort f2bf(float f) {
    union { float f; unsigned u; } v; v.f = f;
    unsigned r = v.u + 0x7FFF + ((v.u >> 16) & 1);
    return (ushort)(r >> 16);
}
__device__ inline float bf2f(ushort u) {
    union { unsigned u; float f; } v; v.u = (unsigned)u << 16; return v.f;
}

// ---------------- x scalar stats: Sx, Sxx ----------------
__global__ void k_xstats(const float* __restrict__ x, float* __restrict__ xs, int n) {
    int lane = threadIdx.x & 63;
    float s = 0.f, q = 0.f;
    for (int i = blockIdx.x * blockDim.x + threadIdx.x; i < n; i += gridDim.x * blockDim.x) {
        float v = x[i];
        s += v; q += v * v;
    }
    #pragma unroll
    for (int off = 32; off >= 1; off >>= 1) {
        s += __shfl_xor(s, off, 64);
        q += __shfl_xor(q, off, 64);
    }
    if (lane == 0) { atomicAdd(&xs[0], s); atomicAdd(&xs[1], q); }
}

// ------- layer-0 hn (bf16): BN params in closed form (h = x*Wn + bnb is rank-1) -------
__global__ void k_hn0(const float* __restrict__ x, const float* __restrict__ xs,
                      const float* __restrict__ Wn, const float* __restrict__ bnb,
                      const float* __restrict__ gamma, const float* __restrict__ beta,
                      ushort* __restrict__ hn, int total4) {
    int i = blockIdx.x * blockDim.x + threadIdx.x;
    if (i >= total4) return;
    int d4 = (i & 31) * 4;
    int n = i >> 5;
    float mx = xs[0] * (1.f / NN);
    float vx = xs[1] * (1.f / NN) - mx * mx;
    float xv = x[n];
    float4 w = *(const float4*)(Wn + d4);
    float4 b = *(const float4*)(bnb + d4);
    float4 g = *(const float4*)(gamma + d4);
    float4 bt = *(const float4*)(beta + d4);
    ushort4 o;
    {
        float mu = fmaf(mx, w.x, b.x), sc = rsqrtf(vx * w.x * w.x + EPS_NORM) * g.x;
        o.x = f2bf(fmaxf(fmaf(fmaf(xv, w.x, b.x) - mu, sc, bt.x), 0.f));
    }
    {
        float mu = fmaf(mx, w.y, b.y), sc = rsqrtf(vx * w.y * w.y + EPS_NORM) * g.y;
        o.y = f2bf(fmaxf(fmaf(fmaf(xv, w.y, b.y) - mu, sc, bt.y), 0.f));
    }
    {
        float mu = fmaf(mx, w.z, b.z), sc = rsqrtf(vx * w.z * w.z + EPS_NORM) * g.z;
        o.z = f2bf(fmaxf(fmaf(fmaf(xv, w.z, b.z) - mu, sc, bt.z), 0.f));
    }
    {
        float mu = fmaf(mx, w.w, b.w), sc = rsqrtf(vx * w.w * w.w + EPS_NORM) * g.w;
        o.w = f2bf(fmaxf(fmaf(fmaf(xv, w.w, b.w) - mu, sc, bt.w), 0.f));
    }
    *(ushort4*)(hn + (size_t)n * DIM + d4) = o;
}

// ------- all weight casts+transposes: W1 [D][H]->[H][D], W2 [H][D]->[D][H] ---
__global__ void k_castAll(const float* __restrict__ W1, const float* __restrict__ W2,
                          ushort* __restrict__ W1t, ushort* __restrict__ W2t) {
    const int chunk = DIM * HID;
    int i = blockIdx.x * blockDim.x + threadIdx.x;
    if (i >= 4 * chunk) return;
    int w = i / chunk;
    int j = i - w * chunk;
    if (w < 2) {
        int r = j / HID, c = j - r * HID;
        W1t[(size_t)w * chunk + (size_t)c * DIM + r] = f2bf(W1[(size_t)w * chunk + j]);
    } else {
        int l = w - 2;
        int r = j / DIM, c = j - r * DIM;
        W2t[(size_t)l * chunk + (size_t)c * HID + r] = f2bf(W2[(size_t)l * chunk + j]);
    }
}

// ---------------- CSR build ----------------
__global__ void k_hist(const int* __restrict__ dst, int* __restrict__ deg, int E) {
    int i = blockIdx.x * blockDim.x + threadIdx.x;
    if (i < E) atomicAdd(&deg[dst[i]], 1);
}

// block b: partials[b] = sum(deg[b*1024 .. b*1024+1023])
__global__ __launch_bounds__(256) void k_scanA(const int* __restrict__ deg,
                                               int* __restrict__ partials, int n) {
    __shared__ int ws[4];
    int b = blockIdx.x;
    int t = threadIdx.x;
    int s = 0;
    #pragma unroll
    for (int i = 0; i < 4; ++i) {
        int idx = b * 1024 + t + i * 256;
        s += (idx < n) ? deg[idx] : 0;
    }
    #pragma unroll
    for (int off = 32; off >= 1; off >>= 1) s += __shfl_xor(s, off, 64);
    if ((t & 63) == 0) ws[t >> 6] = s;
    __syncthreads();
    if (t == 0) partials[b] = ws[0] + ws[1] + ws[2] + ws[3];
}

// single wave: exclusive scan of NB partials -> base[]
__global__ __launch_bounds__(64) void k_scanB(const int* __restrict__ partials,
                                              int* __restrict__ base,
                                              int* __restrict__ row_off) {
    int t = threadIdx.x;
    int v = (t < NB) ? partials[t] : 0;
    int x = v;
    #pragma unroll
    for (int off = 1; off < 64; off <<= 1) {
        int y = __shfl_up(x, off, 64);
        if (t >= off) x += y;
    }
    if (t < NB) base[t] = x - v;
    if (t == 0) row_off[NN] = NE;
}

// block b: scan its 1024 chunk with base[b]; write row_off + cursor
__global__ __launch_bounds__(1024) void k_scanC(const int* __restrict__ deg,
                                                const int* __restrict__ base,
                                                int* __restrict__ row_off,
                                                int* __restrict__ cursor, int n) {
    __shared__ int wsum[16];
    int i = blockIdx.x * 1024 + threadIdx.x;
    int lane = threadIdx.x & 63;
    int wid = threadIdx.x >> 6;
    int v = (i < n) ? deg[i] : 0;
    int x = v;
    #pragma unroll
    for (int off = 1; off < 64; off <<= 1) {
        int y = __shfl_up(x, off, 64);
        if (lane >= off) x += y;
    }
    if (lane == 63) wsum[wid] = x;
    __syncthreads();
    if (wid == 0 && lane < 16) {
        int w = wsum[lane];
        #pragma unroll
        for (int off = 1; off < 16; off <<= 1) {
            int y = __shfl_up(w, off, 64);
            if (lane >= off) w += y;
        }
        wsum[lane] = w;
    }
    __syncthreads();
    int prev = (wid == 0) ? 0 : wsum[wid - 1];
    int excl = base[blockIdx.x] + prev + (x - v);
    if (i < n) { row_off[i] = excl; cursor[i] = excl; }
}

// scatter edge record {src, eid, ea_bits, 0} to CSR slot (one 16B store)
__global__ void k_scatter(const int* __restrict__ src, const int* __restrict__ dst,
                          const float* __restrict__ eattr, int* __restrict__ cursor,
                          int4* __restrict__ erec, int E) {
    int i = blockIdx.x * blockDim.x + threadIdx.x;
    if (i >= E) return;
    int d = dst[i];
    int pos = atomicAdd(&cursor[d], 1);
    erec[pos] = make_int4(src[i], i, __float_as_int(eattr[i]), 0);
}

// ------- BN apply + ReLU -> bf16 hn (finalize fused per-thread from raw stats) -------
__global__ void k_bn_relu(const float* __restrict__ h, const float* __restrict__ stats,
                          const float* __restrict__ gamma, const float* __restrict__ beta,
                          ushort* __restrict__ hn, int total4) {
    int i = blockIdx.x * blockDim.x + threadIdx.x;
    if (i >= total4) return;
    int d4 = (i & 31) * 4;
    int n = i >> 5;
    float4 v = *(const float4*)(h + (size_t)n * DIM + d4);
    float4 s = *(const float4*)(stats + d4);
    float4 q = *(const float4*)(stats + DIM + d4);
    float4 g = *(const float4*)(gamma + d4);
    float4 bt = *(const float4*)(beta + d4);
    ushort4 o;
    {
        float mu = s.x * (1.f / NN), var = q.x * (1.f / NN) - mu * mu;
        float sc = rsqrtf(var + EPS_NORM) * g.x;
        o.x = f2bf(fmaxf(fmaf(v.x - mu, sc, bt.x), 0.f));
    }
    {
        float mu = s.y * (1.f / NN), var = q.y * (1.f / NN) - mu * mu;
        float sc = rsqrtf(var + EPS_NORM) * g.y;
        o.y = f2bf(fmaxf(fmaf(v.y - mu, sc, bt.y), 0.f));
    }
    {
        float mu = s.z * (1.f / NN), var = q.z * (1.f / NN) - mu * mu;
        float sc = rsqrtf(var + EPS_NORM) * g.z;
        o.z = f2bf(fmaxf(fmaf(v.z - mu, sc, bt.z), 0.f));
    }
    {
        float mu = s.w * (1.f / NN), var = q.w * (1.f / NN) - mu * mu;
        float sc = rsqrtf(var + EPS_NORM) * g.w;
        o.w = f2bf(fmaxf(fmaf(v.w - mu, sc, bt.w), 0.f));
    }
    *(ushort4*)(hn + (size_t)n * DIM + d4) = o;
}

// ------- GENConv softmax aggregation: wave per node, lane = 2 channels, unroll-4 -------
__global__ __launch_bounds__(256) void k_agg(const ushort* __restrict__ hn,
                                             const int4* __restrict__ erec,
                                             const int* __restrict__ row_off,
                                             const float* __restrict__ We,
                                             const float* __restrict__ be,
                                             const float* __restrict__ t_all, int l,
                                             ushort* __restrict__ ob, int N) {
    int n = blockIdx.x * 4 + (threadIdx.x >> 6);
    if (n >= N) return;
    int lane = threadIdx.x & 63;
    int d0 = lane * 2;
    float2 we = *(const float2*)(We + d0);
    float2 bd = *(const float2*)(be + d0);
    float t = t_all[l];
    int p0 = row_off[n], p1 = row_off[n + 1];
    int deg = p1 - p0;

    int mp = p0 + lane;
    int s_l = 0; float ea_l = 0.f;
    if (mp < p1) {
        int4 r = erec[mp];
        s_l = r.x; ea_l = __int_as_float(r.z);
    }

    float den0 = 0.f, num0 = 0.f, den1 = 0.f, num1 = 0.f;
    int kmax = deg < 64 ? deg : 64;
    int k = 0;
    for (; k + 4 <= kmax; k += 4) {
        int sA = __shfl(s_l, k, 64), sB = __shfl(s_l, k + 1, 64);
        int sC = __shfl(s_l, k + 2, 64), sD = __shfl(s_l, k + 3, 64);
        float eA = __shfl(ea_l, k, 64), eB = __shfl(ea_l, k + 1, 64);
        float eC = __shfl(ea_l, k + 2, 64), eD = __shfl(ea_l, k + 3, 64);
        uint hA = *(const uint*)(hn + (size_t)sA * DIM + d0);
        uint hB = *(const uint*)(hn + (size_t)sB * DIM + d0);
        uint hC = *(const uint*)(hn + (size_t)sC * DIM + d0);
        uint hD = *(const uint*)(hn + (size_t)sD * DIM + d0);
        {
            float m0 = fmaxf(bf2f((ushort)hA) + fmaf(eA, we.x, bd.x), 0.f) + EPS_MSG;
            float m1 = fmaxf(bf2f((ushort)(hA >> 16)) + fmaf(eA, we.y, bd.y), 0.f) + EPS_MSG;
            float x0 = __expf(m0 * t), x1 = __expf(m1 * t);
            den0 += x0; num0 += m0 * x0; den1 += x1; num1 += m1 * x1;
        }
        {
            float m0 = fmaxf(bf2f((ushort)hB) + fmaf(eB, we.x, bd.x), 0.f) + EPS_MSG;
            float m1 = fmaxf(bf2f((ushort)(hB >> 16)) + fmaf(eB, we.y, bd.y), 0.f) + EPS_MSG;
            float x0 = __expf(m0 * t), x1 = __expf(m1 * t);
            den0 += x0; num0 += m0 * x0; den1 += x1; num1 += m1 * x1;
        }
        {
            float m0 = fmaxf(bf2f((ushort)hC) + fmaf(eC, we.x, bd.x), 0.f) + EPS_MSG;
            float m1 = fmaxf(bf2f((ushort)(hC >> 16)) + fmaf(eC, we.y, bd.y), 0.f) + EPS_MSG;
            float x0 = __expf(m0 * t), x1 = __expf(m1 * t);
            den0 += x0; num0 += m0 * x0; den1 += x1; num1 += m1 * x1;
        }
        {
            float m0 = fmaxf(bf2f((ushort)hD) + fmaf(eD, we.x, bd.x), 0.f) + EPS_MSG;
            float m1 = fmaxf(bf2f((ushort)(hD >> 16)) + fmaf(eD, we.y, bd.y), 0.f) + EPS_MSG;
            float x0 = __expf(m0 * t), x1 = __expf(m1 * t);
            den0 += x0; num0 += m0 * x0; den1 += x1; num1 += m1 * x1;
        }
    }
    for (; k < kmax; ++k) {
        int s = __shfl(s_l, k, 64);
        float ea = __shfl(ea_l, k, 64);
        uint hv = *(const uint*)(hn + (size_t)s * DIM + d0);
        float m0 = fmaxf(bf2f((ushort)hv) + fmaf(ea, we.x, bd.x), 0.f) + EPS_MSG;
        float m1 = fmaxf(bf2f((ushort)(hv >> 16)) + fmaf(ea, we.y, bd.y), 0.f) + EPS_MSG;
        float x0 = __expf(m0 * t), x1 = __expf(m1 * t);
        den0 += x0; num0 += m0 * x0; den1 += x1; num1 += m1 * x1;
    }
    for (int p = p0 + 64; p < p1; ++p) {  // rare: deg > 64
        int4 r = erec[p];
        int s = r.x;
        float ea = __int_as_float(r.z);
        uint hv = *(const uint*)(hn + (size_t)s * DIM + d0);
        float m0 = fmaxf(bf2f((ushort)hv) + fmaf(ea, we.x, bd.x), 0.f) + EPS_MSG;
        float m1 = fmaxf(bf2f((ushort)(hv >> 16)) + fmaf(ea, we.y, bd.y), 0.f) + EPS_MSG;
        float x0 = __expf(m0 * t), x1 = __expf(m1 * t);
        den0 += x0; num0 += m0 * x0; den1 += x1; num1 += m1 * x1;
    }
    uint hr = *(const uint*)(hn + (size_t)n * DIM + d0);
    float a0 = (deg > 0) ? num0 / (den0 + 1e-16f) : 0.f;
    float a1 = (deg > 0) ? num1 / (den1 + 1e-16f) : 0.f;
    uint o = (uint)f2bf(a0 + bf2f((ushort)hr)) |
             ((uint)f2bf(a1 + bf2f((ushort)(hr >> 16))) << 16);
    *(uint*)(ob + (size_t)n * DIM + d0) = o;
}

// ======== fused MLP: z = LN_relu(ob@W1+b1); out = z@W2 + b2 + base. BM=64. ========
// GEMM1 operands direct-from-global (L2-hot); z bf16 in LDS; GEMM2 B direct-from-global.
// FIRST: base = x*Wn+bnb, write h fp32 + per-col stats. else: base = C residual, write hb bf16.
template <int FIRST>
__global__ __launch_bounds__(256) void k_mlp(const ushort* __restrict__ A,
                                             const ushort* __restrict__ B1t,
                                             const float* __restrict__ b1,
                                             const float* __restrict__ g,
                                             const float* __restrict__ bv,
                                             const ushort* __restrict__ B2t,
                                             const float* __restrict__ b2,
                                             const float* __restrict__ x,
                                             const float* __restrict__ Wn,
                                             const float* __restrict__ bnb,
                                             float* __restrict__ C,
                                             ushort* __restrict__ hb,
                                             float* __restrict__ stats) {
    constexpr int LDZ = 264;  // 256 + 8 pad
    __shared__ ushort Zs[64 * LDZ];
    __shared__ float red_s[4][64];
    __shared__ float red_q[4][64];
    __shared__ float murs[2][64];
    const int tid = threadIdx.x;
    const int lane = tid & 63;
    const int wid = tid >> 6;
    const int row0 = blockIdx.x * 64;
    const int wc = wid * 64;   // GEMM1 col strip
    const int l15 = lane & 15;
    const int lq = lane >> 4;

    // ---- GEMM1: 64 x 256, K=128, operands direct from global ----
    f32x4 acc[4][4] = {};
    #pragma unroll
    for (int ks = 0; ks < 4; ++ks) {
        int kk = ks * 32 + lq * 8;
        short8v bfr[4], afr[4];
        #pragma unroll
        for (int f = 0; f < 4; ++f)
            bfr[f] = *(const short8v*)(B1t + (size_t)(wc + f * 16 + l15) * DIM + kk);
        #pragma unroll
        for (int f = 0; f < 4; ++f)
            afr[f] = *(const short8v*)(A + (size_t)(row0 + f * 16 + l15) * DIM + kk);
        #pragma unroll
        for (int mi = 0; mi < 4; ++mi)
            #pragma unroll
            for (int ni = 0; ni < 4; ++ni)
                acc[mi][ni] = __builtin_amdgcn_mfma_f32_16x16x32_bf16(
                    afr[mi], bfr[ni], acc[mi][ni], 0, 0, 0);
    }

    // ---- bias + LN row stats ----
    float bb[4], gg[4], bb2[4];
    #pragma unroll
    for (int ni = 0; ni < 4; ++ni) {
        int col = wc + ni * 16 + l15;
        bb[ni] = b1[col]; gg[ni] = g[col]; bb2[ni] = bv[col];
    }
    #pragma unroll
    for (int mi = 0; mi < 4; ++mi) {
        #pragma unroll
        for (int j = 0; j < 4; ++j) {
            float s = 0.f, q = 0.f;
            #pragma unroll
            for (int ni = 0; ni < 4; ++ni) {
                float v = acc[mi][ni][j] + bb[ni];
                acc[mi][ni][j] = v;
                s += v; q += v * v;
            }
            #pragma unroll
            for (int off = 1; off <= 8; off <<= 1) {
                s += __shfl_xor(s, off, 64);
                q += __shfl_xor(q, off, 64);
            }
            if (l15 == 0) {
                int row = mi * 16 + lq * 4 + j;
                red_s[wid][row] = s;
                red_q[wid][row] = q;
            }
        }
    }
    __syncthreads();
    if (tid < 64) {
        float s = red_s[0][tid] + red_s[1][tid] + red_s[2][tid] + red_s[3][tid];
        float q = red_q[0][tid] + red_q[1][tid] + red_q[2][tid] + red_q[3][tid];
        float mu = s * (1.f / HID);
        float var = q * (1.f / HID) - mu * mu;
        murs[0][tid] = mu;
        murs[1][tid] = rsqrtf(var + EPS_NORM);
    }
    __syncthreads();
    // ---- LN + ReLU -> bf16 into LDS ----
    #pragma unroll
    for (int mi = 0; mi < 4; ++mi) {
        #pragma unroll
        for (int j = 0; j < 4; ++j) {
            int row = mi * 16 + lq * 4 + j;
            float mu = murs[0][row], rs = murs[1][row];
            #pragma unroll
            for (int ni = 0; ni < 4; ++ni) {
                float v = fmaxf(fmaf((acc[mi][ni][j] - mu) * rs, gg[ni], bb2[ni]), 0.f);
                Zs[row * LDZ + wc + ni * 16 + l15] = f2bf(v);
            }
        }
    }
    __syncthreads();

    // ---- GEMM2: 64 x 128, K=256. A from Zs, B direct from global. wave: 32 cols ----
    const int wc2 = wid * 32;
    f32x4 acc2[4][2] = {};
    #pragma unroll
    for (int ks = 0; ks < 8; ++ks) {
        int kk = ks * 32 + lq * 8;
        short8v bf2[2], af2[4];
        #pragma unroll
        for (int f = 0; f < 2; ++f)
            bf2[f] = *(const short8v*)(B2t + (size_t)(wc2 + f * 16 + l15) * HID + kk);
        #pragma unroll
        for (int f = 0; f < 4; ++f)
            af2[f] = *(const short8v*)(Zs + (f * 16 + l15) * LDZ + kk);
        #pragma unroll
        for (int mi = 0; mi < 4; ++mi)
            #pragma unroll
            for (int ni = 0; ni < 2; ++ni)
                acc2[mi][ni] = __builtin_amdgcn_mfma_f32_16x16x32_bf16(
                    af2[mi], bf2[ni], acc2[mi][ni], 0, 0, 0);
    }

    // ---- epilogue ----
    float ssum[2] = {0.f, 0.f};
    float sq[2] = {0.f, 0.f};
    #pragma unroll
    for (int ni = 0; ni < 2; ++ni) {
        int col = wc2 + ni * 16 + l15;
        float bvv = b2[col];
        float wnc = FIRST ? Wn[col] : 0.f;
        float bnc = FIRST ? bnb[col] : 0.f;
        #pragma unroll
        for (int mi = 0; mi < 4; ++mi) {
            int rowb = row0 + mi * 16 + lq * 4;
            #pragma unroll
            for (int j = 0; j < 4; ++j) {
                int gr = rowb + j;
                float base;
                if (FIRST) {
                    float xv = (gr < NN) ? x[gr] : 0.f;
                    base = fmaf(xv, wnc, bnc);
                } else {
                    base = C[(size_t)gr * DIM + col];
                }
                float v = acc2[mi][ni][j] + bvv + base;
                if (FIRST) {
                    C[(size_t)gr * DIM + col] = v;
                    bool ok = gr < NN;
                    ssum[ni] += ok ? v : 0.f;
                    sq[ni] += ok ? v * v : 0.f;
                } else {
                    hb[(size_t)gr * DIM + col] = f2bf(v);
                }
            }
        }
    }
    if (FIRST) {
        #pragma unroll
        for (int ni = 0; ni < 2; ++ni) {
            float s = ssum[ni], q = sq[ni];
            s += __shfl_xor(s, 16, 64); s += __shfl_xor(s, 32, 64);
            q += __shfl_xor(q, 16, 64); q += __shfl_xor(q, 32, 64);
            if (lq == 0) {
                int col = wc2 + ni * 16 + l15;
                atomicAdd(&stats[col], s);
                atomicAdd(&stats[DIM + col], q);
            }
        }
    }
}

// ------- dot predictor, CSR order: wave per node, 4 edges/iter (16 lanes x 8 ch) -------
__global__ __launch_bounds__(256) void k_dot(const ushort* __restrict__ hb,
                                             const int4* __restrict__ erec,
                                             const int* __restrict__ row_off,
                                             float* __restrict__ out, int N) {
    int n = blockIdx.x * 4 + (threadIdx.x >> 6);
    if (n >= N) return;
    int lane = threadIdx.x & 63;
    int sub = lane >> 4;
    int l16 = lane & 15;
    float hd[8];
    {
        ushort8v hv = *(const ushort8v*)(hb + (size_t)n * DIM + l16 * 8);
        #pragma unroll
        for (int j = 0; j < 8; ++j) hd[j] = bf2f(hv[j]);
    }
    int p0 = row_off[n], p1 = row_off[n + 1];
    int deg = p1 - p0;
    int mp = p0 + lane;
    int s_l = 0, e_l = 0;
    if (mp < p1) {
        int4 r = erec[mp];
        s_l = r.x; e_l = r.y;
    }
    int kmax = deg < 64 ? deg : 64;
    for (int k = 0; k < kmax; k += 4) {
        int idx = k + sub;
        bool ok = idx < kmax;
        int s = __shfl(s_l, idx, 64);
        int e = __shfl(e_l, idx, 64);
        ushort8v av = *(const ushort8v*)(hb + (size_t)(ok ? s : n) * DIM + l16 * 8);
        float p = 0.f;
        #pragma unroll
        for (int j = 0; j < 8; ++j) p = fmaf(bf2f(av[j]), hd[j], p);
        p += __shfl_xor(p, 1, 16);
        p += __shfl_xor(p, 2, 16);
        p += __shfl_xor(p, 4, 16);
        p += __shfl_xor(p, 8, 16);
        if (ok && l16 == 0) out[e] = p;
    }
    for (int pb = p0 + 64; pb < p1; pb += 4) {  // rare: deg > 64
        int pe = pb + sub;
        bool ok = pe < p1;
        int s = n, e = 0;
        if (ok) { int4 r = erec[pe]; s = r.x; e = r.y; }
        ushort8v av = *(const ushort8v*)(hb + (size_t)s * DIM + l16 * 8);
        float p = 0.f;
        #pragma unroll
        for (int j = 0; j < 8; ++j) p = fmaf(bf2f(av[j]), hd[j], p);
        p += __shfl_xor(p, 1, 16);
        p += __shfl_xor(p, 2, 16);
        p += __shfl_xor(p, 4, 16);
        p += __shfl_xor(p, 8, 16);
        if (ok && l16 == 0) out[e] = p;
    }
}

extern "C" void kernel_launch(void* const* d_in, const int* in_sizes, int n_in,
                              void* d_out, int out_size, void* d_ws, size_t ws_size,
                              hipStream_t stream) {
    const float* x        = (const float*)d_in[0];
    const int*   ei       = (const int*)d_in[1];
    const float* eattr    = (const float*)d_in[2];
    const float* Wn       = (const float*)d_in[3];
    const float* bnb      = (const float*)d_in[4];
    const float* We       = (const float*)d_in[5];
    const float* be       = (const float*)d_in[6];
    const float* bn_gamma = (const float*)d_in[7];
    const float* bn_beta  = (const float*)d_in[8];
    const float* t_all    = (const float*)d_in[9];
    const float* W1       = (const float*)d_in[10];
    const float* b1       = (const float*)d_in[11];
    const float* ln_g     = (const float*)d_in[12];
    const float* ln_b     = (const float*)d_in[13];
    const float* W2       = (const float*)d_in[14];
    const float* b2       = (const float*)d_in[15];
    float* out = (float*)d_out;

    const int N = NN, E = NE, D = DIM, H = HID;
    const int* src = ei;
    const int* dst = ei + E;

    char* ws = (char*)d_ws;
    auto alloc = [&](size_t bytes) {
        char* p = ws;
        ws += (bytes + 255) & ~(size_t)255;
        return p;
    };
    float*  h       = (float*)alloc((size_t)MPAD * D * 4);
    ushort* ob      = (ushort*)alloc((size_t)MPAD * D * 2);
    ushort* hn      = (ushort*)alloc((size_t)MPAD * D * 2);
    ushort* hb      = (ushort*)alloc((size_t)MPAD * D * 2);
    ushort* W1t     = (ushort*)alloc((size_t)2 * D * H * 2);
    ushort* W2t     = (ushort*)alloc((size_t)2 * D * H * 2);
    int4*   erec    = (int4*)alloc((size_t)E * 16);
    int*    row_off = (int*)alloc((size_t)(N + 1) * 4);
    int*    cursor  = (int*)alloc((size_t)N * 4);
    int*    deg     = (int*)alloc((size_t)N * 4);
    int*    partials= (int*)alloc((size_t)64 * 4);
    int*    pbase   = (int*)alloc((size_t)64 * 4);
    float*  stats   = (float*)alloc((size_t)2 * D * 4);   // 1024 B
    float*  xs      = (float*)alloc((size_t)2 * 4);       // adjacent: one memset covers

    hipMemsetAsync(deg, 0, (size_t)N * 4, stream);
    hipMemsetAsync(stats, 0, 1024 + 8, stream);

    k_xstats<<<64, 256, 0, stream>>>(x, xs, N);
    k_castAll<<<(4 * D * H + 255) / 256, 256, 0, stream>>>(W1, W2, W1t, W2t);
    k_hist<<<(E + 255) / 256, 256, 0, stream>>>(dst, deg, E);
    k_scanA<<<NB, 256, 0, stream>>>(deg, partials, N);
    k_scanB<<<1, 64, 0, stream>>>(partials, pbase, row_off);
    k_scanC<<<NB, 1024, 0, stream>>>(deg, pbase, row_off, cursor, N);
    k_scatter<<<(E + 255) / 256, 256, 0, stream>>>(src, dst, eattr, cursor, erec, E);
    k_hn0<<<(N * 32 + 255) / 256, 256, 0, stream>>>(x, xs, Wn, bnb, bn_gamma, bn_beta,
                                                    hn, N * 32);

    // ---- layer 0 ----
    k_agg<<<(N + 3) / 4, 256, 0, stream>>>(hn, erec, row_off, We, be, t_all, 0, ob, N);
    k_mlp<1><<<MPAD / 64, 256, 0, stream>>>(ob, W1t, b1, ln_g, ln_b, W2t, b2,
                                            x, Wn, bnb, h, hb, stats);
    k_bn_relu<<<(N * 32 + 255) / 256, 256, 0, stream>>>(h, stats, bn_gamma + D, bn_beta + D,
                                                        hn, N * 32);

    // ---- layer 1 ----
    k_agg<<<(N + 3) / 4, 256, 0, stream>>>(hn, erec, row_off, We, be, t_all, 1, ob, N);
    k_mlp<0><<<MPAD / 64, 256, 0, stream>>>(ob, W1t + (size_t)D * H, b1 + H,
                                            ln_g + H, ln_b + H, W2t + (size_t)D * H, b2 + D,
                                            x, Wn, bnb, h, hb, stats);

    k_dot<<<(N + 3) / 4, 256, 0, stream>>>(hb, erec, row_off, out, N);
}

// Round 6
// 383.954 us; speedup vs baseline: 2.9691x; 1.0177x over previous
//
#include <hip/hip_runtime.h>
#include <hip/hip_bf16.h>
#include <math.h>

#define NN 50000
#define NE 600000
#define MPAD 50048      // 1564*32
#define DIM 128
#define HID 256
#define NB 49           // ceil(NN/1024)
#define HIST_BLOCKS ((NE + 255) / 256)
#define CAST_BLOCKS ((4 * DIM * HID) / 256)
#define EPS_MSG 1e-7f
#define EPS_NORM 1e-5f

typedef __attribute__((ext_vector_type(8))) short short8v;
typedef __attribute__((ext_vector_type(8))) unsigned short ushort8v;
typedef __attribute__((ext_vector_type(4))) float f32x4;

__device__ inline ushort f2bf(float f) {
    union { float f; unsigned u; } v; v.f = f;
    unsigned r = v.u + 0x7FFF + ((v.u >> 16) & 1);
    return (ushort)(r >> 16);
}
__device__ inline float bf2f(ushort u) {
    union { unsigned u; float f; } v; v.u = (unsigned)u << 16; return v.f;
}

// ---- fused setup: blocks [0,64) xstats | [64,64+HIST) hist | rest weight cast+T ----
__global__ __launch_bounds__(256) void k_setup(const float* __restrict__ x,
                                               const int* __restrict__ dst,
                                               const float* __restrict__ W1,
                                               const float* __restrict__ W2,
                                               float* __restrict__ xs,
                                               int* __restrict__ deg,
                                               ushort* __restrict__ W1t,
                                               ushort* __restrict__ W2t) {
    int b = blockIdx.x;
    if (b < 64) {
        int lane = threadIdx.x & 63;
        float s = 0.f, q = 0.f;
        for (int i = b * 256 + threadIdx.x; i < NN; i += 64 * 256) {
            float v = x[i];
            s += v; q += v * v;
        }
        #pragma unroll
        for (int off = 32; off >= 1; off >>= 1) {
            s += __shfl_xor(s, off, 64);
            q += __shfl_xor(q, off, 64);
        }
        if (lane == 0) { atomicAdd(&xs[0], s); atomicAdd(&xs[1], q); }
    } else if (b < 64 + HIST_BLOCKS) {
        int i = (b - 64) * 256 + threadIdx.x;
        if (i < NE) atomicAdd(&deg[dst[i]], 1);
    } else {
        const int chunk = DIM * HID;
        int i = (b - 64 - HIST_BLOCKS) * 256 + threadIdx.x;
        int w = i / chunk;
        int j = i - w * chunk;
        if (w < 2) {
            int r = j / HID, c = j - r * HID;
            W1t[(size_t)w * chunk + (size_t)c * DIM + r] = f2bf(W1[(size_t)w * chunk + j]);
        } else {
            int l = w - 2;
            int r = j / DIM, c = j - r * DIM;
            W2t[(size_t)l * chunk + (size_t)c * HID + r] = f2bf(W2[(size_t)l * chunk + j]);
        }
    }
}

// ------- layer-0 hn (bf16): BN params in closed form (h = x*Wn + bnb is rank-1) -------
__global__ void k_hn0(const float* __restrict__ x, const float* __restrict__ xs,
                      const float* __restrict__ Wn, const float* __restrict__ bnb,
                      const float* __restrict__ gamma, const float* __restrict__ beta,
                      ushort* __restrict__ hn, int total4) {
    int i = blockIdx.x * blockDim.x + threadIdx.x;
    if (i >= total4) return;
    int d4 = (i & 31) * 4;
    int n = i >> 5;
    float mx = xs[0] * (1.f / NN);
    float vx = xs[1] * (1.f / NN) - mx * mx;
    float xv = x[n];
    float4 w = *(const float4*)(Wn + d4);
    float4 b = *(const float4*)(bnb + d4);
    float4 g = *(const float4*)(gamma + d4);
    float4 bt = *(const float4*)(beta + d4);
    ushort4 o;
    {
        float mu = fmaf(mx, w.x, b.x), sc = rsqrtf(vx * w.x * w.x + EPS_NORM) * g.x;
        o.x = f2bf(fmaxf(fmaf(fmaf(xv, w.x, b.x) - mu, sc, bt.x), 0.f));
    }
    {
        float mu = fmaf(mx, w.y, b.y), sc = rsqrtf(vx * w.y * w.y + EPS_NORM) * g.y;
        o.y = f2bf(fmaxf(fmaf(fmaf(xv, w.y, b.y) - mu, sc, bt.y), 0.f));
    }
    {
        float mu = fmaf(mx, w.z, b.z), sc = rsqrtf(vx * w.z * w.z + EPS_NORM) * g.z;
        o.z = f2bf(fmaxf(fmaf(fmaf(xv, w.z, b.z) - mu, sc, bt.z), 0.f));
    }
    {
        float mu = fmaf(mx, w.w, b.w), sc = rsqrtf(vx * w.w * w.w + EPS_NORM) * g.w;
        o.w = f2bf(fmaxf(fmaf(fmaf(xv, w.w, b.w) - mu, sc, bt.w), 0.f));
    }
    *(ushort4*)(hn + (size_t)n * DIM + d4) = o;
}

// ---------------- CSR build (multi-block scan) ----------------
__global__ __launch_bounds__(256) void k_scanA(const int* __restrict__ deg,
                                               int* __restrict__ partials, int n) {
    __shared__ int ws[4];
    int b = blockIdx.x;
    int t = threadIdx.x;
    int s = 0;
    #pragma unroll
    for (int i = 0; i < 4; ++i) {
        int idx = b * 1024 + t + i * 256;
        s += (idx < n) ? deg[idx] : 0;
    }
    #pragma unroll
    for (int off = 32; off >= 1; off >>= 1) s += __shfl_xor(s, off, 64);
    if ((t & 63) == 0) ws[t >> 6] = s;
    __syncthreads();
    if (t == 0) partials[b] = ws[0] + ws[1] + ws[2] + ws[3];
}

__global__ __launch_bounds__(64) void k_scanB(const int* __restrict__ partials,
                                              int* __restrict__ base,
                                              int* __restrict__ row_off) {
    int t = threadIdx.x;
    int v = (t < NB) ? partials[t] : 0;
    int x = v;
    #pragma unroll
    for (int off = 1; off < 64; off <<= 1) {
        int y = __shfl_up(x, off, 64);
        if (t >= off) x += y;
    }
    if (t < NB) base[t] = x - v;
    if (t == 0) row_off[NN] = NE;
}

__global__ __launch_bounds__(1024) void k_scanC(const int* __restrict__ deg,
                                                const int* __restrict__ base,
                                                int* __restrict__ row_off,
                                                int* __restrict__ cursor, int n) {
    __shared__ int wsum[16];
    int i = blockIdx.x * 1024 + threadIdx.x;
    int lane = threadIdx.x & 63;
    int wid = threadIdx.x >> 6;
    int v = (i < n) ? deg[i] : 0;
    int x = v;
    #pragma unroll
    for (int off = 1; off < 64; off <<= 1) {
        int y = __shfl_up(x, off, 64);
        if (lane >= off) x += y;
    }
    if (lane == 63) wsum[wid] = x;
    __syncthreads();
    if (wid == 0 && lane < 16) {
        int w = wsum[lane];
        #pragma unroll
        for (int off = 1; off < 16; off <<= 1) {
            int y = __shfl_up(w, off, 64);
            if (lane >= off) w += y;
        }
        wsum[lane] = w;
    }
    __syncthreads();
    int prev = (wid == 0) ? 0 : wsum[wid - 1];
    int excl = base[blockIdx.x] + prev + (x - v);
    if (i < n) { row_off[i] = excl; cursor[i] = excl; }
}

// scatter edge record {src, eid, ea_bits, 0} to CSR slot (one 16B store)
__global__ void k_scatter(const int* __restrict__ src, const int* __restrict__ dst,
                          const float* __restrict__ eattr, int* __restrict__ cursor,
                          int4* __restrict__ erec, int E) {
    int i = blockIdx.x * blockDim.x + threadIdx.x;
    if (i >= E) return;
    int d = dst[i];
    int pos = atomicAdd(&cursor[d], 1);
    erec[pos] = make_int4(src[i], i, __float_as_int(eattr[i]), 0);
}

// ------- BN apply + ReLU -> bf16 hn (finalize fused per-thread from raw stats) -------
__global__ void k_bn_relu(const float* __restrict__ h, const float* __restrict__ stats,
                          const float* __restrict__ gamma, const float* __restrict__ beta,
                          ushort* __restrict__ hn, int total4) {
    int i = blockIdx.x * blockDim.x + threadIdx.x;
    if (i >= total4) return;
    int d4 = (i & 31) * 4;
    int n = i >> 5;
    float4 v = *(const float4*)(h + (size_t)n * DIM + d4);
    float4 s = *(const float4*)(stats + d4);
    float4 q = *(const float4*)(stats + DIM + d4);
    float4 g = *(const float4*)(gamma + d4);
    float4 bt = *(const float4*)(beta + d4);
    ushort4 o;
    {
        float mu = s.x * (1.f / NN), var = q.x * (1.f / NN) - mu * mu;
        float sc = rsqrtf(var + EPS_NORM) * g.x;
        o.x = f2bf(fmaxf(fmaf(v.x - mu, sc, bt.x), 0.f));
    }
    {
        float mu = s.y * (1.f / NN), var = q.y * (1.f / NN) - mu * mu;
        float sc = rsqrtf(var + EPS_NORM) * g.y;
        o.y = f2bf(fmaxf(fmaf(v.y - mu, sc, bt.y), 0.f));
    }
    {
        float mu = s.z * (1.f / NN), var = q.z * (1.f / NN) - mu * mu;
        float sc = rsqrtf(var + EPS_NORM) * g.z;
        o.z = f2bf(fmaxf(fmaf(v.z - mu, sc, bt.z), 0.f));
    }
    {
        float mu = s.w * (1.f / NN), var = q.w * (1.f / NN) - mu * mu;
        float sc = rsqrtf(var + EPS_NORM) * g.w;
        o.w = f2bf(fmaxf(fmaf(v.w - mu, sc, bt.w), 0.f));
    }
    *(ushort4*)(hn + (size_t)n * DIM + d4) = o;
}

// ------- GENConv softmax aggregation: wave per node, lane = 2 channels, unroll-4 -------
__global__ __launch_bounds__(256) void k_agg(const ushort* __restrict__ hn,
                                             const int4* __restrict__ erec,
                                             const int* __restrict__ row_off,
                                             const float* __restrict__ We,
                                             const float* __restrict__ be,
                                             const float* __restrict__ t_all, int l,
                                             ushort* __restrict__ ob, int N) {
    int n = blockIdx.x * 4 + (threadIdx.x >> 6);
    if (n >= N) return;
    int lane = threadIdx.x & 63;
    int d0 = lane * 2;
    float2 we = *(const float2*)(We + d0);
    float2 bd = *(const float2*)(be + d0);
    float t = t_all[l];
    int p0 = row_off[n], p1 = row_off[n + 1];
    int deg = p1 - p0;

    int mp = p0 + lane;
    int s_l = 0; float ea_l = 0.f;
    if (mp < p1) {
        int4 r = erec[mp];
        s_l = r.x; ea_l = __int_as_float(r.z);
    }

    float den0 = 0.f, num0 = 0.f, den1 = 0.f, num1 = 0.f;
    int kmax = deg < 64 ? deg : 64;
    int k = 0;
    for (; k + 4 <= kmax; k += 4) {
        int sA = __shfl(s_l, k, 64), sB = __shfl(s_l, k + 1, 64);
        int sC = __shfl(s_l, k + 2, 64), sD = __shfl(s_l, k + 3, 64);
        float eA = __shfl(ea_l, k, 64), eB = __shfl(ea_l, k + 1, 64);
        float eC = __shfl(ea_l, k + 2, 64), eD = __shfl(ea_l, k + 3, 64);
        uint hA = *(const uint*)(hn + (size_t)sA * DIM + d0);
        uint hB = *(const uint*)(hn + (size_t)sB * DIM + d0);
        uint hC = *(const uint*)(hn + (size_t)sC * DIM + d0);
        uint hD = *(const uint*)(hn + (size_t)sD * DIM + d0);
        {
            float m0 = fmaxf(bf2f((ushort)hA) + fmaf(eA, we.x, bd.x), 0.f) + EPS_MSG;
            float m1 = fmaxf(bf2f((ushort)(hA >> 16)) + fmaf(eA, we.y, bd.y), 0.f) + EPS_MSG;
            float x0 = __expf(m0 * t), x1 = __expf(m1 * t);
            den0 += x0; num0 += m0 * x0; den1 += x1; num1 += m1 * x1;
        }
        {
            float m0 = fmaxf(bf2f((ushort)hB) + fmaf(eB, we.x, bd.x), 0.f) + EPS_MSG;
            float m1 = fmaxf(bf2f((ushort)(hB >> 16)) + fmaf(eB, we.y, bd.y), 0.f) + EPS_MSG;
            float x0 = __expf(m0 * t), x1 = __expf(m1 * t);
            den0 += x0; num0 += m0 * x0; den1 += x1; num1 += m1 * x1;
        }
        {
            float m0 = fmaxf(bf2f((ushort)hC) + fmaf(eC, we.x, bd.x), 0.f) + EPS_MSG;
            float m1 = fmaxf(bf2f((ushort)(hC >> 16)) + fmaf(eC, we.y, bd.y), 0.f) + EPS_MSG;
            float x0 = __expf(m0 * t), x1 = __expf(m1 * t);
            den0 += x0; num0 += m0 * x0; den1 += x1; num1 += m1 * x1;
        }
        {
            float m0 = fmaxf(bf2f((ushort)hD) + fmaf(eD, we.x, bd.x), 0.f) + EPS_MSG;
            float m1 = fmaxf(bf2f((ushort)(hD >> 16)) + fmaf(eD, we.y, bd.y), 0.f) + EPS_MSG;
            float x0 = __expf(m0 * t), x1 = __expf(m1 * t);
            den0 += x0; num0 += m0 * x0; den1 += x1; num1 += m1 * x1;
        }
    }
    for (; k < kmax; ++k) {
        int s = __shfl(s_l, k, 64);
        float ea = __shfl(ea_l, k, 64);
        uint hv = *(const uint*)(hn + (size_t)s * DIM + d0);
        float m0 = fmaxf(bf2f((ushort)hv) + fmaf(ea, we.x, bd.x), 0.f) + EPS_MSG;
        float m1 = fmaxf(bf2f((ushort)(hv >> 16)) + fmaf(ea, we.y, bd.y), 0.f) + EPS_MSG;
        float x0 = __expf(m0 * t), x1 = __expf(m1 * t);
        den0 += x0; num0 += m0 * x0; den1 += x1; num1 += m1 * x1;
    }
    for (int p = p0 + 64; p < p1; ++p) {  // rare: deg > 64
        int4 r = erec[p];
        int s = r.x;
        float ea = __int_as_float(r.z);
        uint hv = *(const uint*)(hn + (size_t)s * DIM + d0);
        float m0 = fmaxf(bf2f((ushort)hv) + fmaf(ea, we.x, bd.x), 0.f) + EPS_MSG;
        float m1 = fmaxf(bf2f((ushort)(hv >> 16)) + fmaf(ea, we.y, bd.y), 0.f) + EPS_MSG;
        float x0 = __expf(m0 * t), x1 = __expf(m1 * t);
        den0 += x0; num0 += m0 * x0; den1 += x1; num1 += m1 * x1;
    }
    uint hr = *(const uint*)(hn + (size_t)n * DIM + d0);
    float a0 = (deg > 0) ? num0 / (den0 + 1e-16f) : 0.f;
    float a1 = (deg > 0) ? num1 / (den1 + 1e-16f) : 0.f;
    uint o = (uint)f2bf(a0 + bf2f((ushort)hr)) |
             ((uint)f2bf(a1 + bf2f((ushort)(hr >> 16))) << 16);
    *(uint*)(ob + (size_t)n * DIM + d0) = o;
}

// ======== fused MLP, BM=32: z = LN_relu(ob@W1+b1); out = z@W2 + b2 + base. ========
// grid = MPAD/32 = 1564 blocks -> ~6 blocks/CU for latency hiding (was 782 -> 14% occ).
// GEMM1/GEMM2 B-operands direct-from-global (L2-hot); z bf16 in LDS (17 KB).
template <int FIRST>
__global__ __launch_bounds__(256) void k_mlp(const ushort* __restrict__ A,
                                             const ushort* __restrict__ B1t,
                                             const float* __restrict__ b1,
                                             const float* __restrict__ g,
                                             const float* __restrict__ bv,
                                             const ushort* __restrict__ B2t,
                                             const float* __restrict__ b2,
                                             const float* __restrict__ x,
                                             const float* __restrict__ Wn,
                                             const float* __restrict__ bnb,
                                             float* __restrict__ C,
                                             ushort* __restrict__ hb,
                                             float* __restrict__ stats) {
    constexpr int LDZ = 264;  // 528 B rows -> bank stride 4 -> <=2-way on b128 reads
    __shared__ ushort Zs[32 * LDZ];
    __shared__ float red_s[4][32];
    __shared__ float red_q[4][32];
    __shared__ float murs[2][32];
    const int tid = threadIdx.x;
    const int lane = tid & 63;
    const int wid = tid >> 6;
    const int row0 = blockIdx.x * 32;
    const int wc = wid * 64;   // GEMM1 col strip
    const int l15 = lane & 15;
    const int lq = lane >> 4;

    // ---- GEMM1: 32 x 256, K=128, operands direct from global ----
    f32x4 acc[2][4] = {};
    #pragma unroll
    for (int ks = 0; ks < 4; ++ks) {
        int kk = ks * 32 + lq * 8;
        short8v bfr[4], afr[2];
        #pragma unroll
        for (int f = 0; f < 4; ++f)
            bfr[f] = *(const short8v*)(B1t + (size_t)(wc + f * 16 + l15) * DIM + kk);
        #pragma unroll
        for (int f = 0; f < 2; ++f)
            afr[f] = *(const short8v*)(A + (size_t)(row0 + f * 16 + l15) * DIM + kk);
        #pragma unroll
        for (int mi = 0; mi < 2; ++mi)
            #pragma unroll
            for (int ni = 0; ni < 4; ++ni)
                acc[mi][ni] = __builtin_amdgcn_mfma_f32_16x16x32_bf16(
                    afr[mi], bfr[ni], acc[mi][ni], 0, 0, 0);
    }

    // ---- bias + LN row stats (rows 0..31) ----
    float bb[4], gg[4], bb2[4];
    #pragma unroll
    for (int ni = 0; ni < 4; ++ni) {
        int col = wc + ni * 16 + l15;
        bb[ni] = b1[col]; gg[ni] = g[col]; bb2[ni] = bv[col];
    }
    #pragma unroll
    for (int mi = 0; mi < 2; ++mi) {
        #pragma unroll
        for (int j = 0; j < 4; ++j) {
            float s = 0.f, q = 0.f;
            #pragma unroll
            for (int ni = 0; ni < 4; ++ni) {
                float v = acc[mi][ni][j] + bb[ni];
                acc[mi][ni][j] = v;
                s += v; q += v * v;
            }
            #pragma unroll
            for (int off = 1; off <= 8; off <<= 1) {
                s += __shfl_xor(s, off, 64);
                q += __shfl_xor(q, off, 64);
            }
            if (l15 == 0) {
                int row = mi * 16 + lq * 4 + j;
                red_s[wid][row] = s;
                red_q[wid][row] = q;
            }
        }
    }
    __syncthreads();
    if (tid < 32) {
        float s = red_s[0][tid] + red_s[1][tid] + red_s[2][tid] + red_s[3][tid];
        float q = red_q[0][tid] + red_q[1][tid] + red_q[2][tid] + red_q[3][tid];
        float mu = s * (1.f / HID);
        float var = q * (1.f / HID) - mu * mu;
        murs[0][tid] = mu;
        murs[1][tid] = rsqrtf(var + EPS_NORM);
    }
    __syncthreads();
    // ---- LN + ReLU -> bf16 into LDS ----
    #pragma unroll
    for (int mi = 0; mi < 2; ++mi) {
        #pragma unroll
        for (int j = 0; j < 4; ++j) {
            int row = mi * 16 + lq * 4 + j;
            float mu = murs[0][row], rs = murs[1][row];
            #pragma unroll
            for (int ni = 0; ni < 4; ++ni) {
                float v = fmaxf(fmaf((acc[mi][ni][j] - mu) * rs, gg[ni], bb2[ni]), 0.f);
                Zs[row * LDZ + wc + ni * 16 + l15] = f2bf(v);
            }
        }
    }
    __syncthreads();

    // ---- GEMM2: 32 x 128, K=256. A from Zs, B direct from global. wave: 32 cols ----
    const int wc2 = wid * 32;
    f32x4 acc2[2][2] = {};
    #pragma unroll
    for (int ks = 0; ks < 8; ++ks) {
        int kk = ks * 32 + lq * 8;
        short8v bf2[2], af2[2];
        #pragma unroll
        for (int f = 0; f < 2; ++f)
            bf2[f] = *(const short8v*)(B2t + (size_t)(wc2 + f * 16 + l15) * HID + kk);
        #pragma unroll
        for (int f = 0; f < 2; ++f)
            af2[f] = *(const short8v*)(Zs + (f * 16 + l15) * LDZ + kk);
        #pragma unroll
        for (int mi = 0; mi < 2; ++mi)
            #pragma unroll
            for (int ni = 0; ni < 2; ++ni)
                acc2[mi][ni] = __builtin_amdgcn_mfma_f32_16x16x32_bf16(
                    af2[mi], bf2[ni], acc2[mi][ni], 0, 0, 0);
    }

    // ---- epilogue ----
    float ssum[2] = {0.f, 0.f};
    float sq[2] = {0.f, 0.f};
    #pragma unroll
    for (int ni = 0; ni < 2; ++ni) {
        int col = wc2 + ni * 16 + l15;
        float bvv = b2[col];
        float wnc = FIRST ? Wn[col] : 0.f;
        float bnc = FIRST ? bnb[col] : 0.f;
        #pragma unroll
        for (int mi = 0; mi < 2; ++mi) {
            int rowb = row0 + mi * 16 + lq * 4;
            #pragma unroll
            for (int j = 0; j < 4; ++j) {
                int gr = rowb + j;
                float base;
                if (FIRST) {
                    float xv = (gr < NN) ? x[gr] : 0.f;
                    base = fmaf(xv, wnc, bnc);
                } else {
                    base = C[(size_t)gr * DIM + col];
                }
                float v = acc2[mi][ni][j] + bvv + base;
                if (FIRST) {
                    C[(size_t)gr * DIM + col] = v;
                    bool ok = gr < NN;
                    ssum[ni] += ok ? v : 0.f;
                    sq[ni] += ok ? v * v : 0.f;
                } else {
                    hb[(size_t)gr * DIM + col] = f2bf(v);
                }
            }
        }
    }
    if (FIRST) {
        #pragma unroll
        for (int ni = 0; ni < 2; ++ni) {
            float s = ssum[ni], q = sq[ni];
            s += __shfl_xor(s, 16, 64); s += __shfl_xor(s, 32, 64);
            q += __shfl_xor(q, 16, 64); q += __shfl_xor(q, 32, 64);
            if (lq == 0) {
                int col = wc2 + ni * 16 + l15;
                atomicAdd(&stats[col], s);
                atomicAdd(&stats[DIM + col], q);
            }
        }
    }
}

// ------- dot predictor, CSR order: wave per node, 4 edges/iter (16 lanes x 8 ch) -------
__global__ __launch_bounds__(256) void k_dot(const ushort* __restrict__ hb,
                                             const int4* __restrict__ erec,
                                             const int* __restrict__ row_off,
                                             float* __restrict__ out, int N) {
    int n = blockIdx.x * 4 + (threadIdx.x >> 6);
    if (n >= N) return;
    int lane = threadIdx.x & 63;
    int sub = lane >> 4;
    int l16 = lane & 15;
    float hd[8];
    {
        ushort8v hv = *(const ushort8v*)(hb + (size_t)n * DIM + l16 * 8);
        #pragma unroll
        for (int j = 0; j < 8; ++j) hd[j] = bf2f(hv[j]);
    }
    int p0 = row_off[n], p1 = row_off[n + 1];
    int deg = p1 - p0;
    int mp = p0 + lane;
    int s_l = 0, e_l = 0;
    if (mp < p1) {
        int4 r = erec[mp];
        s_l = r.x; e_l = r.y;
    }
    int kmax = deg < 64 ? deg : 64;
    for (int k = 0; k < kmax; k += 4) {
        int idx = k + sub;
        bool ok = idx < kmax;
        int s = __shfl(s_l, idx, 64);
        int e = __shfl(e_l, idx, 64);
        ushort8v av = *(const ushort8v*)(hb + (size_t)(ok ? s : n) * DIM + l16 * 8);
        float p = 0.f;
        #pragma unroll
        for (int j = 0; j < 8; ++j) p = fmaf(bf2f(av[j]), hd[j], p);
        p += __shfl_xor(p, 1, 16);
        p += __shfl_xor(p, 2, 16);
        p += __shfl_xor(p, 4, 16);
        p += __shfl_xor(p, 8, 16);
        if (ok && l16 == 0) out[e] = p;
    }
    for (int pb = p0 + 64; pb < p1; pb += 4) {  // rare: deg > 64
        int pe = pb + sub;
        bool ok = pe < p1;
        int s = n, e = 0;
        if (ok) { int4 r = erec[pe]; s = r.x; e = r.y; }
        ushort8v av = *(const ushort8v*)(hb + (size_t)s * DIM + l16 * 8);
        float p = 0.f;
        #pragma unroll
        for (int j = 0; j < 8; ++j) p = fmaf(bf2f(av[j]), hd[j], p);
        p += __shfl_xor(p, 1, 16);
        p += __shfl_xor(p, 2, 16);
        p += __shfl_xor(p, 4, 16);
        p += __shfl_xor(p, 8, 16);
        if (ok && l16 == 0) out[e] = p;
    }
}

extern "C" void kernel_launch(void* const* d_in, const int* in_sizes, int n_in,
                              void* d_out, int out_size, void* d_ws, size_t ws_size,
                              hipStream_t stream) {
    const float* x        = (const float*)d_in[0];
    const int*   ei       = (const int*)d_in[1];
    const float* eattr    = (const float*)d_in[2];
    const float* Wn       = (const float*)d_in[3];
    const float* bnb      = (const float*)d_in[4];
    const float* We       = (const float*)d_in[5];
    const float* be       = (const float*)d_in[6];
    const float* bn_gamma = (const float*)d_in[7];
    const float* bn_beta  = (const float*)d_in[8];
    const float* t_all    = (const float*)d_in[9];
    const float* W1       = (const float*)d_in[10];
    const float* b1       = (const float*)d_in[11];
    const float* ln_g     = (const float*)d_in[12];
    const float* ln_b     = (const float*)d_in[13];
    const float* W2       = (const float*)d_in[14];
    const float* b2       = (const float*)d_in[15];
    float* out = (float*)d_out;

    const int N = NN, E = NE, D = DIM, H = HID;
    const int* src = ei;
    const int* dst = ei + E;

    char* ws = (char*)d_ws;
    auto alloc = [&](size_t bytes) {
        char* p = ws;
        ws += (bytes + 255) & ~(size_t)255;
        return p;
    };
    float*  h       = (float*)alloc((size_t)MPAD * D * 4);
    ushort* ob      = (ushort*)alloc((size_t)MPAD * D * 2);
    ushort* hn      = (ushort*)alloc((size_t)MPAD * D * 2);
    ushort* hb      = (ushort*)alloc((size_t)MPAD * D * 2);
    ushort* W1t     = (ushort*)alloc((size_t)2 * D * H * 2);
    ushort* W2t     = (ushort*)alloc((size_t)2 * D * H * 2);
    int4*   erec    = (int4*)alloc((size_t)E * 16);
    int*    row_off = (int*)alloc((size_t)(N + 1) * 4);
    int*    cursor  = (int*)alloc((size_t)N * 4);
    int*    deg     = (int*)alloc((size_t)N * 4);
    int*    partials= (int*)alloc((size_t)64 * 4);
    int*    pbase   = (int*)alloc((size_t)64 * 4);
    float*  stats   = (float*)alloc((size_t)2 * D * 4);   // 1024 B
    float*  xs      = (float*)alloc((size_t)2 * 4);       // adjacent: one memset covers

    hipMemsetAsync(deg, 0, (size_t)N * 4, stream);
    hipMemsetAsync(stats, 0, 1024 + 8, stream);

    k_setup<<<64 + HIST_BLOCKS + CAST_BLOCKS, 256, 0, stream>>>(x, dst, W1, W2,
                                                                xs, deg, W1t, W2t);
    k_scanA<<<NB, 256, 0, stream>>>(deg, partials, N);
    k_scanB<<<1, 64, 0, stream>>>(partials, pbase, row_off);
    k_scanC<<<NB, 1024, 0, stream>>>(deg, pbase, row_off, cursor, N);
    k_scatter<<<(E + 255) / 256, 256, 0, stream>>>(src, dst, eattr, cursor, erec, E);
    k_hn0<<<(N * 32 + 255) / 256, 256, 0, stream>>>(x, xs, Wn, bnb, bn_gamma, bn_beta,
                                                    hn, N * 32);

    // ---- layer 0 ----
    k_agg<<<(N + 3) / 4, 256, 0, stream>>>(hn, erec, row_off, We, be, t_all, 0, ob, N);
    k_mlp<1><<<MPAD / 32, 256, 0, stream>>>(ob, W1t, b1, ln_g, ln_b, W2t, b2,
                                            x, Wn, bnb, h, hb, stats);
    k_bn_relu<<<(N * 32 + 255) / 256, 256, 0, stream>>>(h, stats, bn_gamma + D, bn_beta + D,
                                                        hn, N * 32);

    // ---- layer 1 ----
    k_agg<<<(N + 3) / 4, 256, 0, stream>>>(hn, erec, row_off, We, be, t_all, 1, ob, N);
    k_mlp<0><<<MPAD / 32, 256, 0, stream>>>(ob, W1t + (size_t)D * H, b1 + H,
                                            ln_g + H, ln_b + H, W2t + (size_t)D * H, b2 + D,
                                            x, Wn, bnb, h, hb, stats);

    k_dot<<<(N + 3) / 4, 256, 0, stream>>>(hb, erec, row_off, out, N);
}

// Round 7
// 361.676 us; speedup vs baseline: 3.1520x; 1.0616x over previous
//
#include <hip/hip_runtime.h>
#include <hip/hip_bf16.h>
#include <math.h>

#define NN 50000
#define NE 600000
#define MPAD 50048      // 1564*32
#define NT (MPAD / 32)  // 1564 tiles
#define DIM 128
#define HID 256
#define NB 49           // ceil(NN/1024)
#define HIST_BLOCKS ((NE + 255) / 256)
#define CAST_BLOCKS ((4 * DIM * HID) / 256)
#define EPS_MSG 1e-7f
#define EPS_NORM 1e-5f

typedef __attribute__((ext_vector_type(8))) short short8v;
typedef __attribute__((ext_vector_type(8))) unsigned short ushort8v;
typedef __attribute__((ext_vector_type(4))) float f32x4;

__device__ inline ushort f2bf(float f) {
    union { float f; unsigned u; } v; v.f = f;
    unsigned r = v.u + 0x7FFF + ((v.u >> 16) & 1);
    return (ushort)(r >> 16);
}
__device__ inline float bf2f(ushort u) {
    union { unsigned u; float f; } v; v.u = (unsigned)u << 16; return v.f;
}

// ---- fused setup: blocks [0,64) xstats | [64,64+HIST) hist | rest weight cast+T ----
__global__ __launch_bounds__(256) void k_setup(const float* __restrict__ x,
                                               const int* __restrict__ dst,
                                               const float* __restrict__ W1,
                                               const float* __restrict__ W2,
                                               float* __restrict__ xs,
                                               int* __restrict__ deg,
                                               ushort* __restrict__ W1t,
                                               ushort* __restrict__ W2t) {
    int b = blockIdx.x;
    if (b < 64) {
        int lane = threadIdx.x & 63;
        float s = 0.f, q = 0.f;
        for (int i = b * 256 + threadIdx.x; i < NN; i += 64 * 256) {
            float v = x[i];
            s += v; q += v * v;
        }
        #pragma unroll
        for (int off = 32; off >= 1; off >>= 1) {
            s += __shfl_xor(s, off, 64);
            q += __shfl_xor(q, off, 64);
        }
        if (lane == 0) { atomicAdd(&xs[0], s); atomicAdd(&xs[1], q); }
    } else if (b < 64 + HIST_BLOCKS) {
        int i = (b - 64) * 256 + threadIdx.x;
        if (i < NE) atomicAdd(&deg[dst[i]], 1);
    } else {
        const int chunk = DIM * HID;
        int i = (b - 64 - HIST_BLOCKS) * 256 + threadIdx.x;
        int w = i / chunk;
        int j = i - w * chunk;
        if (w < 2) {
            int r = j / HID, c = j - r * HID;
            W1t[(size_t)w * chunk + (size_t)c * DIM + r] = f2bf(W1[(size_t)w * chunk + j]);
        } else {
            int l = w - 2;
            int r = j / DIM, c = j - r * DIM;
            W2t[(size_t)l * chunk + (size_t)c * HID + r] = f2bf(W2[(size_t)l * chunk + j]);
        }
    }
}

// ------- layer-0 hn (bf16): BN params in closed form (h = x*Wn + bnb is rank-1) -------
__global__ void k_hn0(const float* __restrict__ x, const float* __restrict__ xs,
                      const float* __restrict__ Wn, const float* __restrict__ bnb,
                      const float* __restrict__ gamma, const float* __restrict__ beta,
                      ushort* __restrict__ hn, int total4) {
    int i = blockIdx.x * blockDim.x + threadIdx.x;
    if (i >= total4) return;
    int d4 = (i & 31) * 4;
    int n = i >> 5;
    float mx = xs[0] * (1.f / NN);
    float vx = xs[1] * (1.f / NN) - mx * mx;
    float xv = x[n];
    float4 w = *(const float4*)(Wn + d4);
    float4 b = *(const float4*)(bnb + d4);
    float4 g = *(const float4*)(gamma + d4);
    float4 bt = *(const float4*)(beta + d4);
    ushort4 o;
    {
        float mu = fmaf(mx, w.x, b.x), sc = rsqrtf(vx * w.x * w.x + EPS_NORM) * g.x;
        o.x = f2bf(fmaxf(fmaf(fmaf(xv, w.x, b.x) - mu, sc, bt.x), 0.f));
    }
    {
        float mu = fmaf(mx, w.y, b.y), sc = rsqrtf(vx * w.y * w.y + EPS_NORM) * g.y;
        o.y = f2bf(fmaxf(fmaf(fmaf(xv, w.y, b.y) - mu, sc, bt.y), 0.f));
    }
    {
        float mu = fmaf(mx, w.z, b.z), sc = rsqrtf(vx * w.z * w.z + EPS_NORM) * g.z;
        o.z = f2bf(fmaxf(fmaf(fmaf(xv, w.z, b.z) - mu, sc, bt.z), 0.f));
    }
    {
        float mu = fmaf(mx, w.w, b.w), sc = rsqrtf(vx * w.w * w.w + EPS_NORM) * g.w;
        o.w = f2bf(fmaxf(fmaf(fmaf(xv, w.w, b.w) - mu, sc, bt.w), 0.f));
    }
    *(ushort4*)(hn + (size_t)n * DIM + d4) = o;
}

// ---------------- CSR build (multi-block scan) ----------------
__global__ __launch_bounds__(256) void k_scanA(const int* __restrict__ deg,
                                               int* __restrict__ partials, int n) {
    __shared__ int ws[4];
    int b = blockIdx.x;
    int t = threadIdx.x;
    int s = 0;
    #pragma unroll
    for (int i = 0; i < 4; ++i) {
        int idx = b * 1024 + t + i * 256;
        s += (idx < n) ? deg[idx] : 0;
    }
    #pragma unroll
    for (int off = 32; off >= 1; off >>= 1) s += __shfl_xor(s, off, 64);
    if ((t & 63) == 0) ws[t >> 6] = s;
    __syncthreads();
    if (t == 0) partials[b] = ws[0] + ws[1] + ws[2] + ws[3];
}

__global__ __launch_bounds__(64) void k_scanB(const int* __restrict__ partials,
                                              int* __restrict__ base,
                                              int* __restrict__ row_off) {
    int t = threadIdx.x;
    int v = (t < NB) ? partials[t] : 0;
    int x = v;
    #pragma unroll
    for (int off = 1; off < 64; off <<= 1) {
        int y = __shfl_up(x, off, 64);
        if (t >= off) x += y;
    }
    if (t < NB) base[t] = x - v;
    if (t == 0) row_off[NN] = NE;
}

__global__ __launch_bounds__(1024) void k_scanC(const int* __restrict__ deg,
                                                const int* __restrict__ base,
                                                int* __restrict__ row_off,
                                                int* __restrict__ cursor, int n) {
    __shared__ int wsum[16];
    int i = blockIdx.x * 1024 + threadIdx.x;
    int lane = threadIdx.x & 63;
    int wid = threadIdx.x >> 6;
    int v = (i < n) ? deg[i] : 0;
    int x = v;
    #pragma unroll
    for (int off = 1; off < 64; off <<= 1) {
        int y = __shfl_up(x, off, 64);
        if (lane >= off) x += y;
    }
    if (lane == 63) wsum[wid] = x;
    __syncthreads();
    if (wid == 0 && lane < 16) {
        int w = wsum[lane];
        #pragma unroll
        for (int off = 1; off < 16; off <<= 1) {
            int y = __shfl_up(w, off, 64);
            if (lane >= off) w += y;
        }
        wsum[lane] = w;
    }
    __syncthreads();
    int prev = (wid == 0) ? 0 : wsum[wid - 1];
    int excl = base[blockIdx.x] + prev + (x - v);
    if (i < n) { row_off[i] = excl; cursor[i] = excl; }
}

// scatter edge record {src, eid, ea_bits, 0} to CSR slot (one 16B store)
__global__ void k_scatter(const int* __restrict__ src, const int* __restrict__ dst,
                          const float* __restrict__ eattr, int* __restrict__ cursor,
                          int4* __restrict__ erec, int E) {
    int i = blockIdx.x * blockDim.x + threadIdx.x;
    if (i >= E) return;
    int d = dst[i];
    int pos = atomicAdd(&cursor[d], 1);
    erec[pos] = make_int4(src[i], i, __float_as_int(eattr[i]), 0);
}

// ------- BN apply + ReLU -> bf16 hn (finalize fused per-thread from raw stats) -------
__global__ void k_bn_relu(const float* __restrict__ h, const float* __restrict__ stats,
                          const float* __restrict__ gamma, const float* __restrict__ beta,
                          ushort* __restrict__ hn, int total4) {
    int i = blockIdx.x * blockDim.x + threadIdx.x;
    if (i >= total4) return;
    int d4 = (i & 31) * 4;
    int n = i >> 5;
    float4 v = *(const float4*)(h + (size_t)n * DIM + d4);
    float4 s = *(const float4*)(stats + d4);
    float4 q = *(const float4*)(stats + DIM + d4);
    float4 g = *(const float4*)(gamma + d4);
    float4 bt = *(const float4*)(beta + d4);
    ushort4 o;
    {
        float mu = s.x * (1.f / NN), var = q.x * (1.f / NN) - mu * mu;
        float sc = rsqrtf(var + EPS_NORM) * g.x;
        o.x = f2bf(fmaxf(fmaf(v.x - mu, sc, bt.x), 0.f));
    }
    {
        float mu = s.y * (1.f / NN), var = q.y * (1.f / NN) - mu * mu;
        float sc = rsqrtf(var + EPS_NORM) * g.y;
        o.y = f2bf(fmaxf(fmaf(v.y - mu, sc, bt.y), 0.f));
    }
    {
        float mu = s.z * (1.f / NN), var = q.z * (1.f / NN) - mu * mu;
        float sc = rsqrtf(var + EPS_NORM) * g.z;
        o.z = f2bf(fmaxf(fmaf(v.z - mu, sc, bt.z), 0.f));
    }
    {
        float mu = s.w * (1.f / NN), var = q.w * (1.f / NN) - mu * mu;
        float sc = rsqrtf(var + EPS_NORM) * g.w;
        o.w = f2bf(fmaxf(fmaf(v.w - mu, sc, bt.w), 0.f));
    }
    *(ushort4*)(hn + (size_t)n * DIM + d4) = o;
}

// ------- GENConv softmax aggregation: wave per node, lane = 2 channels, unroll-4 -------
__global__ __launch_bounds__(256) void k_agg(const ushort* __restrict__ hn,
                                             const int4* __restrict__ erec,
                                             const int* __restrict__ row_off,
                                             const float* __restrict__ We,
                                             const float* __restrict__ be,
                                             const float* __restrict__ t_all, int l,
                                             ushort* __restrict__ ob, int N) {
    int n = blockIdx.x * 4 + (threadIdx.x >> 6);
    if (n >= N) return;
    int lane = threadIdx.x & 63;
    int d0 = lane * 2;
    float2 we = *(const float2*)(We + d0);
    float2 bd = *(const float2*)(be + d0);
    float t = t_all[l];
    int p0 = row_off[n], p1 = row_off[n + 1];
    int deg = p1 - p0;

    int mp = p0 + lane;
    int s_l = 0; float ea_l = 0.f;
    if (mp < p1) {
        int4 r = erec[mp];
        s_l = r.x; ea_l = __int_as_float(r.z);
    }

    float den0 = 0.f, num0 = 0.f, den1 = 0.f, num1 = 0.f;
    int kmax = deg < 64 ? deg : 64;
    int k = 0;
    for (; k + 4 <= kmax; k += 4) {
        int sA = __shfl(s_l, k, 64), sB = __shfl(s_l, k + 1, 64);
        int sC = __shfl(s_l, k + 2, 64), sD = __shfl(s_l, k + 3, 64);
        float eA = __shfl(ea_l, k, 64), eB = __shfl(ea_l, k + 1, 64);
        float eC = __shfl(ea_l, k + 2, 64), eD = __shfl(ea_l, k + 3, 64);
        uint hA = *(const uint*)(hn + (size_t)sA * DIM + d0);
        uint hB = *(const uint*)(hn + (size_t)sB * DIM + d0);
        uint hC = *(const uint*)(hn + (size_t)sC * DIM + d0);
        uint hD = *(const uint*)(hn + (size_t)sD * DIM + d0);
        {
            float m0 = fmaxf(bf2f((ushort)hA) + fmaf(eA, we.x, bd.x), 0.f) + EPS_MSG;
            float m1 = fmaxf(bf2f((ushort)(hA >> 16)) + fmaf(eA, we.y, bd.y), 0.f) + EPS_MSG;
            float x0 = __expf(m0 * t), x1 = __expf(m1 * t);
            den0 += x0; num0 += m0 * x0; den1 += x1; num1 += m1 * x1;
        }
        {
            float m0 = fmaxf(bf2f((ushort)hB) + fmaf(eB, we.x, bd.x), 0.f) + EPS_MSG;
            float m1 = fmaxf(bf2f((ushort)(hB >> 16)) + fmaf(eB, we.y, bd.y), 0.f) + EPS_MSG;
            float x0 = __expf(m0 * t), x1 = __expf(m1 * t);
            den0 += x0; num0 += m0 * x0; den1 += x1; num1 += m1 * x1;
        }
        {
            float m0 = fmaxf(bf2f((ushort)hC) + fmaf(eC, we.x, bd.x), 0.f) + EPS_MSG;
            float m1 = fmaxf(bf2f((ushort)(hC >> 16)) + fmaf(eC, we.y, bd.y), 0.f) + EPS_MSG;
            float x0 = __expf(m0 * t), x1 = __expf(m1 * t);
            den0 += x0; num0 += m0 * x0; den1 += x1; num1 += m1 * x1;
        }
        {
            float m0 = fmaxf(bf2f((ushort)hD) + fmaf(eD, we.x, bd.x), 0.f) + EPS_MSG;
            float m1 = fmaxf(bf2f((ushort)(hD >> 16)) + fmaf(eD, we.y, bd.y), 0.f) + EPS_MSG;
            float x0 = __expf(m0 * t), x1 = __expf(m1 * t);
            den0 += x0; num0 += m0 * x0; den1 += x1; num1 += m1 * x1;
        }
    }
    for (; k < kmax; ++k) {
        int s = __shfl(s_l, k, 64);
        float ea = __shfl(ea_l, k, 64);
        uint hv = *(const uint*)(hn + (size_t)s * DIM + d0);
        float m0 = fmaxf(bf2f((ushort)hv) + fmaf(ea, we.x, bd.x), 0.f) + EPS_MSG;
        float m1 = fmaxf(bf2f((ushort)(hv >> 16)) + fmaf(ea, we.y, bd.y), 0.f) + EPS_MSG;
        float x0 = __expf(m0 * t), x1 = __expf(m1 * t);
        den0 += x0; num0 += m0 * x0; den1 += x1; num1 += m1 * x1;
    }
    for (int p = p0 + 64; p < p1; ++p) {  // rare: deg > 64
        int4 r = erec[p];
        int s = r.x;
        float ea = __int_as_float(r.z);
        uint hv = *(const uint*)(hn + (size_t)s * DIM + d0);
        float m0 = fmaxf(bf2f((ushort)hv) + fmaf(ea, we.x, bd.x), 0.f) + EPS_MSG;
        float m1 = fmaxf(bf2f((ushort)(hv >> 16)) + fmaf(ea, we.y, bd.y), 0.f) + EPS_MSG;
        float x0 = __expf(m0 * t), x1 = __expf(m1 * t);
        den0 += x0; num0 += m0 * x0; den1 += x1; num1 += m1 * x1;
    }
    uint hr = *(const uint*)(hn + (size_t)n * DIM + d0);
    float a0 = (deg > 0) ? num0 / (den0 + 1e-16f) : 0.f;
    float a1 = (deg > 0) ? num1 / (den1 + 1e-16f) : 0.f;
    uint o = (uint)f2bf(a0 + bf2f((ushort)hr)) |
             ((uint)f2bf(a1 + bf2f((ushort)(hr >> 16))) << 16);
    *(uint*)(ob + (size_t)n * DIM + d0) = o;
}

// ======== fused MLP, persistent blocks + weights-in-registers. ========
// grid = 512 blocks (2/CU), each grid-strides over 32-row tiles. W1/W2 fragments
// loaded ONCE per block into 128 VGPRs; per tile only 8 A-loads + 48 MFMA + LN remain.
template <int FIRST>
__global__ __launch_bounds__(256, 2) void k_mlp(const ushort* __restrict__ A,
                                                const ushort* __restrict__ B1t,
                                                const float* __restrict__ b1,
                                                const float* __restrict__ g,
                                                const float* __restrict__ bv,
                                                const ushort* __restrict__ B2t,
                                                const float* __restrict__ b2,
                                                const float* __restrict__ x,
                                                const float* __restrict__ Wn,
                                                const float* __restrict__ bnb,
                                                float* __restrict__ C,
                                                ushort* __restrict__ hb,
                                                float* __restrict__ stats) {
    constexpr int LDZ = 264;  // 528 B rows -> <=2-way bank aliasing on b128 reads
    __shared__ ushort Zs[32 * LDZ];
    __shared__ float red_s[4][32];
    __shared__ float red_q[4][32];
    __shared__ float murs[2][32];
    const int tid = threadIdx.x;
    const int lane = tid & 63;
    const int wid = tid >> 6;
    const int wc = wid * 64;   // GEMM1 col strip
    const int wc2 = wid * 32;  // GEMM2 col strip
    const int l15 = lane & 15;
    const int lq = lane >> 4;

    // ---- resident weight fragments (loaded once) ----
    short8v bw1[4][4];  // [ks][f] GEMM1: K=128
    #pragma unroll
    for (int ks = 0; ks < 4; ++ks)
        #pragma unroll
        for (int f = 0; f < 4; ++f)
            bw1[ks][f] = *(const short8v*)(B1t + (size_t)(wc + f * 16 + l15) * DIM +
                                           ks * 32 + lq * 8);
    short8v bw2[8][2];  // [ks][f] GEMM2: K=256
    #pragma unroll
    for (int ks = 0; ks < 8; ++ks)
        #pragma unroll
        for (int f = 0; f < 2; ++f)
            bw2[ks][f] = *(const short8v*)(B2t + (size_t)(wc2 + f * 16 + l15) * HID +
                                           ks * 32 + lq * 8);
    float bb[4], gg[4], lb[4];
    #pragma unroll
    for (int ni = 0; ni < 4; ++ni) {
        int col = wc + ni * 16 + l15;
        bb[ni] = b1[col]; gg[ni] = g[col]; lb[ni] = bv[col];
    }
    float b2v[2], wnc[2], bnc[2];
    #pragma unroll
    for (int ni = 0; ni < 2; ++ni) {
        int col = wc2 + ni * 16 + l15;
        b2v[ni] = b2[col];
        wnc[ni] = FIRST ? Wn[col] : 0.f;
        bnc[ni] = FIRST ? bnb[col] : 0.f;
    }

    for (int tile = blockIdx.x; tile < NT; tile += gridDim.x) {
        const int row0 = tile * 32;
        // ---- A fragment loads (the only per-tile global loads on the GEMM path) ----
        short8v afr[4][2];
        #pragma unroll
        for (int ks = 0; ks < 4; ++ks)
            #pragma unroll
            for (int f = 0; f < 2; ++f)
                afr[ks][f] = *(const short8v*)(A + (size_t)(row0 + f * 16 + l15) * DIM +
                                               ks * 32 + lq * 8);
        // ---- GEMM1: 32 x 256, K=128 ----
        f32x4 acc[2][4] = {};
        #pragma unroll
        for (int ks = 0; ks < 4; ++ks)
            #pragma unroll
            for (int mi = 0; mi < 2; ++mi)
                #pragma unroll
                for (int ni = 0; ni < 4; ++ni)
                    acc[mi][ni] = __builtin_amdgcn_mfma_f32_16x16x32_bf16(
                        afr[ks][mi], bw1[ks][ni], acc[mi][ni], 0, 0, 0);

        // ---- bias + LN row stats ----
        #pragma unroll
        for (int mi = 0; mi < 2; ++mi) {
            #pragma unroll
            for (int j = 0; j < 4; ++j) {
                float s = 0.f, q = 0.f;
                #pragma unroll
                for (int ni = 0; ni < 4; ++ni) {
                    float v = acc[mi][ni][j] + bb[ni];
                    acc[mi][ni][j] = v;
                    s += v; q += v * v;
                }
                #pragma unroll
                for (int off = 1; off <= 8; off <<= 1) {
                    s += __shfl_xor(s, off, 64);
                    q += __shfl_xor(q, off, 64);
                }
                if (l15 == 0) {
                    int row = mi * 16 + lq * 4 + j;
                    red_s[wid][row] = s;
                    red_q[wid][row] = q;
                }
            }
        }
        __syncthreads();
        if (tid < 32) {
            float s = red_s[0][tid] + red_s[1][tid] + red_s[2][tid] + red_s[3][tid];
            float q = red_q[0][tid] + red_q[1][tid] + red_q[2][tid] + red_q[3][tid];
            float mu = s * (1.f / HID);
            float var = q * (1.f / HID) - mu * mu;
            murs[0][tid] = mu;
            murs[1][tid] = rsqrtf(var + EPS_NORM);
        }
        __syncthreads();
        // ---- LN + ReLU -> bf16 into LDS ----
        #pragma unroll
        for (int mi = 0; mi < 2; ++mi) {
            #pragma unroll
            for (int j = 0; j < 4; ++j) {
                int row = mi * 16 + lq * 4 + j;
                float mu = murs[0][row], rs = murs[1][row];
                #pragma unroll
                for (int ni = 0; ni < 4; ++ni) {
                    float v = fmaxf(fmaf((acc[mi][ni][j] - mu) * rs, gg[ni], lb[ni]), 0.f);
                    Zs[row * LDZ + wc + ni * 16 + l15] = f2bf(v);
                }
            }
        }
        __syncthreads();

        // ---- GEMM2: 32 x 128, K=256. A from Zs, B resident in regs ----
        f32x4 acc2[2][2] = {};
        #pragma unroll
        for (int ks = 0; ks < 8; ++ks) {
            short8v af2[2];
            #pragma unroll
            for (int f = 0; f < 2; ++f)
                af2[f] = *(const short8v*)(Zs + (f * 16 + l15) * LDZ + ks * 32 + lq * 8);
            #pragma unroll
            for (int mi = 0; mi < 2; ++mi)
                #pragma unroll
                for (int ni = 0; ni < 2; ++ni)
                    acc2[mi][ni] = __builtin_amdgcn_mfma_f32_16x16x32_bf16(
                        af2[mi], bw2[ks][ni], acc2[mi][ni], 0, 0, 0);
        }

        // ---- epilogue ----
        float ssum[2] = {0.f, 0.f};
        float sq[2] = {0.f, 0.f};
        #pragma unroll
        for (int ni = 0; ni < 2; ++ni) {
            int col = wc2 + ni * 16 + l15;
            #pragma unroll
            for (int mi = 0; mi < 2; ++mi) {
                int rowb = row0 + mi * 16 + lq * 4;
                #pragma unroll
                for (int j = 0; j < 4; ++j) {
                    int gr = rowb + j;
                    float base;
                    if (FIRST) {
                        float xv = (gr < NN) ? x[gr] : 0.f;
                        base = fmaf(xv, wnc[ni], bnc[ni]);
                    } else {
                        base = C[(size_t)gr * DIM + col];
                    }
                    float v = acc2[mi][ni][j] + b2v[ni] + base;
                    if (FIRST) {
                        C[(size_t)gr * DIM + col] = v;
                        bool ok = gr < NN;
                        ssum[ni] += ok ? v : 0.f;
                        sq[ni] += ok ? v * v : 0.f;
                    } else {
                        hb[(size_t)gr * DIM + col] = f2bf(v);
                    }
                }
            }
        }
        if (FIRST) {
            #pragma unroll
            for (int ni = 0; ni < 2; ++ni) {
                float s = ssum[ni], q = sq[ni];
                s += __shfl_xor(s, 16, 64); s += __shfl_xor(s, 32, 64);
                q += __shfl_xor(q, 16, 64); q += __shfl_xor(q, 32, 64);
                if (lq == 0) {
                    int col = wc2 + ni * 16 + l15;
                    atomicAdd(&stats[col], s);
                    atomicAdd(&stats[DIM + col], q);
                }
            }
        }
        __syncthreads();  // protect Zs before next tile's writes
    }
}

// ------- dot predictor, CSR order: wave per node, 4 edges/iter (16 lanes x 8 ch) -------
__global__ __launch_bounds__(256) void k_dot(const ushort* __restrict__ hb,
                                             const int4* __restrict__ erec,
                                             const int* __restrict__ row_off,
                                             float* __restrict__ out, int N) {
    int n = blockIdx.x * 4 + (threadIdx.x >> 6);
    if (n >= N) return;
    int lane = threadIdx.x & 63;
    int sub = lane >> 4;
    int l16 = lane & 15;
    float hd[8];
    {
        ushort8v hv = *(const ushort8v*)(hb + (size_t)n * DIM + l16 * 8);
        #pragma unroll
        for (int j = 0; j < 8; ++j) hd[j] = bf2f(hv[j]);
    }
    int p0 = row_off[n], p1 = row_off[n + 1];
    int deg = p1 - p0;
    int mp = p0 + lane;
    int s_l = 0, e_l = 0;
    if (mp < p1) {
        int4 r = erec[mp];
        s_l = r.x; e_l = r.y;
    }
    int kmax = deg < 64 ? deg : 64;
    for (int k = 0; k < kmax; k += 4) {
        int idx = k + sub;
        bool ok = idx < kmax;
        int s = __shfl(s_l, idx, 64);
        int e = __shfl(e_l, idx, 64);
        ushort8v av = *(const ushort8v*)(hb + (size_t)(ok ? s : n) * DIM + l16 * 8);
        float p = 0.f;
        #pragma unroll
        for (int j = 0; j < 8; ++j) p = fmaf(bf2f(av[j]), hd[j], p);
        p += __shfl_xor(p, 1, 16);
        p += __shfl_xor(p, 2, 16);
        p += __shfl_xor(p, 4, 16);
        p += __shfl_xor(p, 8, 16);
        if (ok && l16 == 0) out[e] = p;
    }
    for (int pb = p0 + 64; pb < p1; pb += 4) {  // rare: deg > 64
        int pe = pb + sub;
        bool ok = pe < p1;
        int s = n, e = 0;
        if (ok) { int4 r = erec[pe]; s = r.x; e = r.y; }
        ushort8v av = *(const ushort8v*)(hb + (size_t)s * DIM + l16 * 8);
        float p = 0.f;
        #pragma unroll
        for (int j = 0; j < 8; ++j) p = fmaf(bf2f(av[j]), hd[j], p);
        p += __shfl_xor(p, 1, 16);
        p += __shfl_xor(p, 2, 16);
        p += __shfl_xor(p, 4, 16);
        p += __shfl_xor(p, 8, 16);
        if (ok && l16 == 0) out[e] = p;
    }
}

extern "C" void kernel_launch(void* const* d_in, const int* in_sizes, int n_in,
                              void* d_out, int out_size, void* d_ws, size_t ws_size,
                              hipStream_t stream) {
    const float* x        = (const float*)d_in[0];
    const int*   ei       = (const int*)d_in[1];
    const float* eattr    = (const float*)d_in[2];
    const float* Wn       = (const float*)d_in[3];
    const float* bnb      = (const float*)d_in[4];
    const float* We       = (const float*)d_in[5];
    const float* be       = (const float*)d_in[6];
    const float* bn_gamma = (const float*)d_in[7];
    const float* bn_beta  = (const float*)d_in[8];
    const float* t_all    = (const float*)d_in[9];
    const float* W1       = (const float*)d_in[10];
    const float* b1       = (const float*)d_in[11];
    const float* ln_g     = (const float*)d_in[12];
    const float* ln_b     = (const float*)d_in[13];
    const float* W2       = (const float*)d_in[14];
    const float* b2       = (const float*)d_in[15];
    float* out = (float*)d_out;

    const int N = NN, E = NE, D = DIM, H = HID;
    const int* src = ei;
    const int* dst = ei + E;

    char* ws = (char*)d_ws;
    auto alloc = [&](size_t bytes) {
        char* p = ws;
        ws += (bytes + 255) & ~(size_t)255;
        return p;
    };
    float*  h       = (float*)alloc((size_t)MPAD * D * 4);
    ushort* ob      = (ushort*)alloc((size_t)MPAD * D * 2);
    ushort* hn      = (ushort*)alloc((size_t)MPAD * D * 2);
    ushort* hb      = (ushort*)alloc((size_t)MPAD * D * 2);
    ushort* W1t     = (ushort*)alloc((size_t)2 * D * H * 2);
    ushort* W2t     = (ushort*)alloc((size_t)2 * D * H * 2);
    int4*   erec    = (int4*)alloc((size_t)E * 16);
    int*    row_off = (int*)alloc((size_t)(N + 1) * 4);
    int*    cursor  = (int*)alloc((size_t)N * 4);
    int*    deg     = (int*)alloc((size_t)N * 4);
    int*    partials= (int*)alloc((size_t)64 * 4);
    int*    pbase   = (int*)alloc((size_t)64 * 4);
    float*  stats   = (float*)alloc((size_t)2 * D * 4);   // 1024 B
    float*  xs      = (float*)alloc((size_t)2 * 4);       // adjacent: one memset covers

    hipMemsetAsync(deg, 0, (size_t)N * 4, stream);
    hipMemsetAsync(stats, 0, 1024 + 8, stream);

    k_setup<<<64 + HIST_BLOCKS + CAST_BLOCKS, 256, 0, stream>>>(x, dst, W1, W2,
                                                                xs, deg, W1t, W2t);
    k_scanA<<<NB, 256, 0, stream>>>(deg, partials, N);
    k_scanB<<<1, 64, 0, stream>>>(partials, pbase, row_off);
    k_scanC<<<NB, 1024, 0, stream>>>(deg, pbase, row_off, cursor, N);
    k_scatter<<<(E + 255) / 256, 256, 0, stream>>>(src, dst, eattr, cursor, erec, E);
    k_hn0<<<(N * 32 + 255) / 256, 256, 0, stream>>>(x, xs, Wn, bnb, bn_gamma, bn_beta,
                                                    hn, N * 32);

    // ---- layer 0 ----
    k_agg<<<(N + 3) / 4, 256, 0, stream>>>(hn, erec, row_off, We, be, t_all, 0, ob, N);
    k_mlp<1><<<512, 256, 0, stream>>>(ob, W1t, b1, ln_g, ln_b, W2t, b2,
                                      x, Wn, bnb, h, hb, stats);
    k_bn_relu<<<(N * 32 + 255) / 256, 256, 0, stream>>>(h, stats, bn_gamma + D, bn_beta + D,
                                                        hn, N * 32);

    // ---- layer 1 ----
    k_agg<<<(N + 3) / 4, 256, 0, stream>>>(hn, erec, row_off, We, be, t_all, 1, ob, N);
    k_mlp<0><<<512, 256, 0, stream>>>(ob, W1t + (size_t)D * H, b1 + H,
                                      ln_g + H, ln_b + H, W2t + (size_t)D * H, b2 + D,
                                      x, Wn, bnb, h, hb, stats);

    k_dot<<<(N + 3) / 4, 256, 0, stream>>>(hb, erec, row_off, out, N);
}